// Round 4
// baseline (205.234 us; speedup 1.0000x reference)
//
#include <hip/hip_runtime.h>
#include <hip/hip_bf16.h>
#include <hip/hip_fp16.h>

#define N_NODES   100000
#define N_EDGES   1600000
#define N_GRAPHS  1024
#define EMB       32
#define HID       64
#define N_CLASSES 10
#define SCAN_BLOCKS 391   // ceil(100000/256)
#define NCOMBO 153        // 17 shape ids x 9 color ids
#define BUCK_NODES 448    // nodes per dst-bucket
#define NBUCK 224         // ceil(100000/448)
#define BIN_CAP 8192      // per-bucket staging capacity (mean 7143, +12 sigma)
#define EPB 4096          // edges per binA block

typedef _Float16 f16x8 __attribute__((ext_vector_type(8)));
typedef float f32x4 __attribute__((ext_vector_type(4)));

// ---------------- prep: combo[v] + sorted-batch segment boundaries ----------------
// batch is sorted, so per-graph counts = gstart[g+1]-gstart[g].  Zero atomics.
__global__ __launch_bounds__(256) void prep_kernel(
    const int* __restrict__ sid, const int* __restrict__ cid,
    const int* __restrict__ batch, int* __restrict__ combo, int* __restrict__ gstart) {
    int v = blockIdx.x * 256 + threadIdx.x;
    if (v < N_NODES) {
        combo[v] = sid[v] * 9 + cid[v];
        int b = batch[v];
        int bp = (v == 0) ? -1 : batch[v - 1];
        for (int g = bp + 1; g <= b; ++g) gstart[g] = v;      // boundary (usually 0 iters)
        if (v == N_NODES - 1) {
            for (int g = b + 1; g <= N_GRAPHS; ++g) gstart[g] = N_NODES;
        }
    }
}

// ---------------- combined table (fp16): TCh[s*9+c][j] = (st[s]@W1)[j] + (ct[c]@W1)[j] ----------------
__global__ __launch_bounds__(64) void tc_kernel(
    const float* __restrict__ st, const float* __restrict__ ct,
    const float* __restrict__ W1, __half* __restrict__ TCh) {
    int r = blockIdx.x, j = threadIdx.x;
    int s = r / 9, c = r % 9;
    float acc = 0.0f;
    if (s != 0) {
#pragma unroll
        for (int k = 0; k < EMB; ++k) acc = fmaf(st[s * EMB + k], W1[k * HID + j], acc);
    }
    if (c != 0) {
#pragma unroll
        for (int k = 0; k < EMB; ++k) acc = fmaf(ct[c * EMB + k], W1[k * HID + j], acc);
    }
    TCh[r * HID + j] = __float2half_rn(acc);
}

// ---------------- binA: block-local counting sort by dst-bucket, split-plane flush ----------------
__global__ __launch_bounds__(512) void binA_kernel(
    const int* __restrict__ src, const int* __restrict__ dst,
    const int* __restrict__ combo, int* __restrict__ gcur,
    int* __restrict__ gbinx, int* __restrict__ gbiny) {
    __shared__ int2 stg[EPB];            // 32 KB
    __shared__ int hist[NBUCK];
    __shared__ int base[NBUCK + 1];
    __shared__ int gstart[NBUCK];
    __shared__ int scanbuf[256];
    int t = threadIdx.x;
    int e0 = blockIdx.x * EPB;
    for (int i = t; i < NBUCK; i += 512) hist[i] = 0;
    __syncthreads();

    int2 myq[8];
    int mybo[8];
#pragma unroll
    for (int i = 0; i < 8; ++i) {
        int e = e0 + t + i * 512;
        if (e < N_EDGES) {
            int d = dst[e];
            int s = src[e];
            unsigned b = (unsigned)d / BUCK_NODES;
            int off = atomicAdd(&hist[b], 1);
            myq[i].x = s | (combo[s] << 17);
            myq[i].y = d;
            mybo[i] = (int)(b << 16) | off;
        } else {
            mybo[i] = -1;
        }
    }
    __syncthreads();

    int h = (t < NBUCK) ? hist[t] : 0;
    if (t < 256) scanbuf[t] = h;
    __syncthreads();
#pragma unroll
    for (int off = 1; off < 256; off <<= 1) {
        int x = (t < 256 && t >= off) ? scanbuf[t - off] : 0;
        __syncthreads();
        if (t < 256) scanbuf[t] += x;
        __syncthreads();
    }
    if (t < NBUCK) base[t] = scanbuf[t] - h;
    if (t == 0) base[NBUCK] = scanbuf[255];
    __syncthreads();
#pragma unroll
    for (int i = 0; i < 8; ++i) {
        if (mybo[i] >= 0) {
            int b = mybo[i] >> 16, off = mybo[i] & 0xFFFF;
            stg[base[b] + off] = myq[i];
        }
    }
    if (t < NBUCK) {
        int n = hist[t];
        gstart[t] = n ? atomicAdd(&gcur[t], n) : 0;
    }
    __syncthreads();
    int total = base[NBUCK];
    for (int i = t; i < total; i += 512) {
        int2 q = stg[i];
        unsigned b = (unsigned)q.y / BUCK_NODES;
        size_t pos = (size_t)b * BIN_CAP + gstart[b] + (i - base[b]);
        gbinx[pos] = q.x;
        gbiny[pos] = q.y;
    }
}

// ---------------- bucket: per-bucket degrees -> dis + rowptr (dst-plane only; scan folded) ----------------
__global__ __launch_bounds__(512) void bucket_kernel(
    const int* __restrict__ gbiny, const int* __restrict__ gcur,
    float* __restrict__ dis, int* __restrict__ rowptr) {
    __shared__ int ldeg[BUCK_NODES];
    __shared__ int s[512];
    __shared__ int sc[256];
    int b = blockIdx.x, t = threadIdx.x;
    if (t < 256) sc[t] = (t < NBUCK) ? gcur[t] : 0;
    for (int i = t; i < BUCK_NODES; i += 512) ldeg[i] = 0;
    __syncthreads();
    // block-local inclusive scan of gcur (replaces bscan kernel)
#pragma unroll
    for (int off = 1; off < 256; off <<= 1) {
        int x = (t < 256 && t >= off) ? sc[t - off] : 0;
        __syncthreads();
        if (t < 256) sc[t] += x;
        __syncthreads();
    }
    int bb = (b == 0) ? 0 : sc[b - 1];    // exclusive bucket base
    int n = gcur[b];
    const int* mybin = gbiny + (size_t)b * BIN_CAP;
    for (int i = t; i < n; i += 512)
        atomicAdd(&ldeg[mybin[i] - b * BUCK_NODES], 1);
    __syncthreads();
    int d = (t < BUCK_NODES) ? ldeg[t] : 0;
    int v = b * BUCK_NODES + t;
    if (t < BUCK_NODES && v < N_NODES) dis[v] = rsqrtf(1.0f + (float)d);
    s[t] = d;
    __syncthreads();
#pragma unroll
    for (int off = 1; off < 512; off <<= 1) {
        int x = (t >= off) ? s[t - off] : 0;
        __syncthreads();
        s[t] += x;
        __syncthreads();
    }
    if (t < BUCK_NODES && v < N_NODES) rowptr[v] = bb + s[t] - d;
    if (b == 0 && t == 0) rowptr[N_NODES] = N_EDGES;
}

// ---------------- binB: per-bucket fine scatter to CSR (1024 threads) ----------------
// epack.x = (src << 15) | (combo*128)   [src: 17b, combo byte-offset: 15b]
// epack.y = dis[src] as float bits
__global__ __launch_bounds__(1024) void binB_kernel(
    const int* __restrict__ gbinx, const int* __restrict__ gbiny,
    const int* __restrict__ gcur,
    const int* __restrict__ rowptr, const float* __restrict__ dis,
    int2* __restrict__ epack) {
    __shared__ int curs[BUCK_NODES];
    int b = blockIdx.x, t = threadIdx.x;
    for (int i = t; i < BUCK_NODES; i += 1024) curs[i] = 0;
    __syncthreads();
    int n = gcur[b];
    const int* mx = gbinx + (size_t)b * BIN_CAP;
    const int* my = gbiny + (size_t)b * BIN_CAP;
    for (int i = t; i < n; i += 1024) {
        int qx = mx[i];
        int qy = my[i];
        int local = qy - b * BUCK_NODES;
        int r = atomicAdd(&curs[local], 1);
        unsigned sx = (unsigned)qx;
        int srci = (int)(sx & 0x1FFFF);
        int comboOff = (int)((sx >> 17) * 128u);   // <= 19456, fits 15 bits
        int2 rec;
        rec.x = (srci << 15) | comboOff;
        rec.y = __float_as_int(dis[srci]);
        epack[rowptr[qy] + r] = rec;
    }
}

// ---------------- fused layer-1 aggregate + MFMA mm2 ----------------
// Block = 16 consecutive nodes; wave w owns nodes v0..v0+3 for aggregation.
// Edge prefetch: lanes 16n..16n+15 hold edges 0-15 (q1) and 16-31 (q2) of node n.
// Edge consume: readlane broadcast + LDS TC gather.
// mm2: block-cooperative X(16x64,fp16) @ W2(64x64,fp16) via 2x mfma_f32_16x16x32_f16.
#define AGG_CHUNK(Q, LBASE, J0)                                                \
    _Pragma("unroll")                                                          \
    for (int i = 0; i < 8; ++i) {                                              \
        int off = __builtin_amdgcn_readlane((Q).x, (LBASE) + i) & 0x7FFF;      \
        int wb  = __builtin_amdgcn_readlane((Q).y, (LBASE) + i);               \
        off = ((J0) + i < cnt) ? off : 0;                                      \
        wb  = ((J0) + i < cnt) ? wb  : 0;                                      \
        __half tv = *(const __half*)((const char*)TCs + (off + lane2));        \
        acc = fmaf(__int_as_float(wb), __half2float(tv), acc);                 \
    }

#define AGG_NODE(N, RS, RE, DV, CO)                                            \
    {                                                                          \
        int deg = (RE) - (RS);                                                 \
        int cnt = deg > 32 ? 32 : deg;                                         \
        float acc = 0.0f;                                                      \
        AGG_CHUNK(q1, (N)*16, 0)                                               \
        if (cnt > 8)  { AGG_CHUNK(q1, (N)*16 + 8, 8) }                         \
        if (cnt > 16) { AGG_CHUNK(q2, (N)*16, 16) }                            \
        if (cnt > 24) { AGG_CHUNK(q2, (N)*16 + 8, 24) }                        \
        if (deg > 32) {                                                        \
            for (int e = (RS) + 32; e < (RE); ++e) {                           \
                int2 q = epack[e];                                             \
                __half tv = *(const __half*)((const char*)TCs +                \
                                             ((q.x & 0x7FFF) + lane2));        \
                acc = fmaf(__int_as_float(q.y), __half2float(tv), acc);        \
            }                                                                  \
        }                                                                      \
        __half hv = *(const __half*)((const char*)TCs + ((CO) + lane2));       \
        float val = (DV) * fmaf(__half2float(hv), (DV), acc) + bias;           \
        val = val > 0.0f ? val : 0.0f;                                         \
        xsA[w * 4 + (N)][lane] = __float2half_rn(val * (DV));                  \
    }

__global__ __launch_bounds__(256, 6) void agg1_mm2_kernel(
    const int2* __restrict__ epack, const int* __restrict__ rowptr,
    const int* __restrict__ combo, const float* __restrict__ dis,
    const __half* __restrict__ TCh, const float* __restrict__ W2,
    const float* __restrict__ b1, __half* __restrict__ h2s) {
    __shared__ __align__(16) __half TCs[NCOMBO * HID];  // 19,584 B
    __shared__ __align__(16) __half xsA[16][72];        //  2,304 B (stride 72: bank spread)
    __shared__ __align__(16) __half Dst[16 * 64];       //  2,048 B
    int t = threadIdx.x;
    int lane = t & 63, w = t >> 6;
    int lane2 = lane * 2;
    int vb = blockIdx.x * 16;
    int v0 = vb + w * 4;

    // per-lane sliced edge prefetch (longest latency chain - issue first)
    int sub = lane >> 4, sl = lane & 15;
    int rb = rowptr[v0 + sub];
    int2 q1 = epack[rb + sl];        // node sub, edges 0..15
    int2 q2 = epack[rb + 16 + sl];   // node sub, edges 16..31 (may over-read: ok)

    // scalar row pointers
    int r0 = __builtin_amdgcn_readfirstlane(rowptr[v0]);
    int r1 = __builtin_amdgcn_readfirstlane(rowptr[v0 + 1]);
    int r2 = __builtin_amdgcn_readfirstlane(rowptr[v0 + 2]);
    int r3 = __builtin_amdgcn_readfirstlane(rowptr[v0 + 3]);
    int r4 = __builtin_amdgcn_readfirstlane(rowptr[v0 + 4]);

    // per-node epilogue scalars (issue early)
    float d0 = dis[v0], d1 = dis[v0 + 1], d2 = dis[v0 + 2], d3 = dis[v0 + 3];
    int o0 = combo[v0] << 7, o1 = combo[v0 + 1] << 7;
    int o2 = combo[v0 + 2] << 7, o3 = combo[v0 + 3] << 7;
    float bias = b1[lane];

    // B fragments of W2 for this wave's 16 output cols (built once, from global)
    f16x8 bf0, bf1;
    {
        int colw = (w << 4) + (lane & 15);
        int kb = (lane >> 4) * 8;
#pragma unroll
        for (int i = 0; i < 8; ++i) {
            bf0[i] = (_Float16)W2[(kb + i) * HID + colw];
            bf1[i] = (_Float16)W2[(32 + kb + i) * HID + colw];
        }
    }

    // stage TC table to LDS
    {
        const int4* s4 = (const int4*)TCh;
        int4* dd4 = (int4*)TCs;
        for (int i = t; i < NCOMBO * HID * 2 / 16; i += 256) dd4[i] = s4[i];
    }
    __syncthreads();   // also drains the edge prefetch

    AGG_NODE(0, r0, r1, d0, o0)
    AGG_NODE(1, r1, r2, d1, o1)
    AGG_NODE(2, r2, r3, d2, o2)
    AGG_NODE(3, r3, r4, d3, o3)

    __syncthreads();   // all 16 rows of xsA ready

    // A fragments: row = lane&15 (node), k = (lane>>4)*8 + i  (+32 for 2nd MFMA)
    const __half* xa = &xsA[lane & 15][0];
    f16x8 a0 = *(const f16x8*)(xa + (lane >> 4) * 8);
    f16x8 a1 = *(const f16x8*)(xa + 32 + (lane >> 4) * 8);
    f32x4 dacc = {0.0f, 0.0f, 0.0f, 0.0f};
    dacc = __builtin_amdgcn_mfma_f32_16x16x32_f16(a0, bf0, dacc, 0, 0, 0);
    dacc = __builtin_amdgcn_mfma_f32_16x16x32_f16(a1, bf1, dacc, 0, 0, 0);

    // D: col = lane&15 (within wave's 16-col block), row = (lane>>4)*4 + i (node)
    {
        int colg = (w << 4) + (lane & 15);
#pragma unroll
        for (int i = 0; i < 4; ++i)
            Dst[((lane >> 4) * 4 + i) * 64 + colg] = __float2half_rn(dacc[i]);
    }
    __syncthreads();

    // coalesced block store: 16 nodes x 64 feats fp16 = 2048 B contiguous
    {
        const uint2* ds2 = (const uint2*)Dst;
        uint2* go = (uint2*)(h2s + (size_t)vb * HID);
        go[t] = ds2[t];
    }
}

// ---------------- layer-2 paired-node edge accumulate ----------------
// Dual 8-deep gather pipelines (16 loads in flight per wave).  sxA/sxB are the
// per-lane prefetched epack.x for edges rs..rs+63 of each node; offsets are
// broadcast per edge via readlane (SGPR index), gathers are 2B/lane from the
// 128B h2s row (fully coalesced per edge).
__device__ __forceinline__ void agg2_pair(
    const int* __restrict__ epackx, const __half* __restrict__ h2s,
    int sxA, int rsA, int reA, int sxB, int rsB, int reB,
    int lane2, float* outA, float* outB) {
    int degA = reA - rsA, degB = reB - rsB;
    int cntA = degA > 64 ? 64 : degA;
    int cntB = degB > 64 ? 64 : degB;
    int voA = (int)(((unsigned)sxA >> 15) << 7);   // src*128 byte offset
    int voB = (int)(((unsigned)sxB >> 15) << 7);
    float aA = 0.0f, aB = 0.0f;
    int cmax = cntA > cntB ? cntA : cntB;
    for (int j = 0; j < cmax; j += 8) {
        float gA[8], gB[8];
        bool dA = j < cntA, dB = j < cntB;   // wave-uniform
        if (dA) {
#pragma unroll
            for (int i = 0; i < 8; ++i) {
                int off = __builtin_amdgcn_readlane(voA, (j + i) & 63);
                float v = __half2float(*(const __half*)((const char*)h2s + (off + lane2)));
                gA[i] = (j + i < cntA) ? v : 0.0f;
            }
        }
        if (dB) {
#pragma unroll
            for (int i = 0; i < 8; ++i) {
                int off = __builtin_amdgcn_readlane(voB, (j + i) & 63);
                float v = __half2float(*(const __half*)((const char*)h2s + (off + lane2)));
                gB[i] = (j + i < cntB) ? v : 0.0f;
            }
        }
        if (dA) {
#pragma unroll
            for (int i = 0; i < 8; ++i) aA += gA[i];
        }
        if (dB) {
#pragma unroll
            for (int i = 0; i < 8; ++i) aB += gB[i];
        }
    }
    // deg>64 fallback (Poisson(16): never triggers for this input; correctness only)
    for (int e = rsA + 64; e < reA; ++e) {
        int off = (int)(((unsigned)epackx[e * 2] >> 15) << 7);
        aA += __half2float(*(const __half*)((const char*)h2s + (off + lane2)));
    }
    for (int e = rsB + 64; e < reB; ++e) {
        int off = (int)(((unsigned)epackx[e * 2] >> 15) << 7);
        aB += __half2float(*(const __half*)((const char*)h2s + (off + lane2)));
    }
    *outA = aA;
    *outB = aB;
}

// ---------------- layer-2 aggregate + pool: 4 nodes/wave, run-merged atomics ----------------
__global__ __launch_bounds__(256, 6) void agg2_pool_kernel(
    const int2* __restrict__ epack, const int* __restrict__ rowptr,
    const __half* __restrict__ h2s, const float* __restrict__ dis,
    const float* __restrict__ b2, const int* __restrict__ batch,
    float* __restrict__ pooled) {
    int t = threadIdx.x, lane = t & 63, w = t >> 6;
    int lane2 = lane * 2;
    const int* epackx = (const int*)epack;
    int v0 = (blockIdx.x * 4 + w) * 4;   // grid 6250

    int r0 = __builtin_amdgcn_readfirstlane(rowptr[v0]);
    int r1 = __builtin_amdgcn_readfirstlane(rowptr[v0 + 1]);
    int r2 = __builtin_amdgcn_readfirstlane(rowptr[v0 + 2]);
    int r3 = __builtin_amdgcn_readfirstlane(rowptr[v0 + 3]);
    int r4 = __builtin_amdgcn_readfirstlane(rowptr[v0 + 4]);

    int ia = r0 + lane; ia = ia < N_EDGES ? ia : N_EDGES - 1;
    int ib = r1 + lane; ib = ib < N_EDGES ? ib : N_EDGES - 1;
    int ic = r2 + lane; ic = ic < N_EDGES ? ic : N_EDGES - 1;
    int id = r3 + lane; id = id < N_EDGES ? id : N_EDGES - 1;
    int sa = epackx[ia * 2];
    int sb = epackx[ib * 2];
    int sc = epackx[ic * 2];
    int sd = epackx[id * 2];

    float bv = b2[lane];
    float acc0, acc1, acc2, acc3;
    agg2_pair(epackx, h2s, sa, r0, r1, sb, r1, r2, lane2, &acc0, &acc1);
    agg2_pair(epackx, h2s, sc, r2, r3, sd, r3, r4, lane2, &acc2, &acc3);

#define AGG2_VAL(V, ACC, OUT)                                                  \
    {                                                                          \
        float dv = dis[V];                                                     \
        float self = __half2float(h2s[(size_t)(V) * HID + lane]);              \
        float val = dv * ((ACC) + self) + bv;                                  \
        OUT = val > 0.0f ? val : 0.0f;                                         \
    }
    float val0, val1, val2, val3;
    AGG2_VAL(v0, acc0, val0)
    AGG2_VAL(v0 + 1, acc1, val1)
    AGG2_VAL(v0 + 2, acc2, val2)
    AGG2_VAL(v0 + 3, acc3, val3)
#undef AGG2_VAL

    int g0 = __builtin_amdgcn_readfirstlane(batch[v0]);
    int g1 = __builtin_amdgcn_readfirstlane(batch[v0 + 1]);
    int g2 = __builtin_amdgcn_readfirstlane(batch[v0 + 2]);
    int g3 = __builtin_amdgcn_readfirstlane(batch[v0 + 3]);
    // batch is sorted: merge same-graph contributions into one atomic per run
    float s = val0; int g = g0;
    if (g1 == g) { s += val1; } else { unsafeAtomicAdd(&pooled[g * HID + lane], s); g = g1; s = val1; }
    if (g2 == g) { s += val2; } else { unsafeAtomicAdd(&pooled[g * HID + lane], s); g = g2; s = val2; }
    if (g3 == g) { s += val3; } else { unsafeAtomicAdd(&pooled[g * HID + lane], s); g = g3; s = val3; }
    unsafeAtomicAdd(&pooled[g * HID + lane], s);
}

// ---------------- logits ----------------
__global__ __launch_bounds__(64) void logits_kernel(
    const float* __restrict__ pooled, const int* __restrict__ gstart,
    const float* __restrict__ Wl, const float* __restrict__ bl,
    float* __restrict__ out) {
    __shared__ float row[HID];
    int g = blockIdx.x, t = threadIdx.x;
    int c = gstart[g + 1] - gstart[g]; if (c < 1) c = 1;
    row[t] = pooled[g * HID + t] / (float)c;
    __syncthreads();
    if (t < N_CLASSES) {
        float acc = bl[t];
#pragma unroll
        for (int k = 0; k < HID; ++k) acc = fmaf(row[k], Wl[k * N_CLASSES + t], acc);
        out[g * N_CLASSES + t] = acc;
    }
}

extern "C" void kernel_launch(void* const* d_in, const int* in_sizes, int n_in,
                              void* d_out, int out_size, void* d_ws, size_t ws_size,
                              hipStream_t stream) {
    const int*   shape_id = (const int*)d_in[0];
    const int*   color_id = (const int*)d_in[1];
    const int*   edge_idx = (const int*)d_in[2];
    const int*   batch    = (const int*)d_in[3];
    const float* st       = (const float*)d_in[4];
    const float* ct       = (const float*)d_in[5];
    const float* W1       = (const float*)d_in[6];
    const float* b1       = (const float*)d_in[7];
    const float* W2       = (const float*)d_in[8];
    const float* b2       = (const float*)d_in[9];
    const float* Wl       = (const float*)d_in[10];
    const float* bl       = (const float*)d_in[11];
    float* out = (float*)d_out;

    const int* src = edge_idx;
    const int* dst = edge_idx + N_EDGES;

    // workspace layout
    char* ws = (char*)d_ws;
    int*    combo   = (int*)   (ws + 0);            //   400,384 B
    float*  dis     = (float*) (ws + 400384);       //   400,384 B
    int*    gstart  = (int*)   (ws + 801792);       //     4,112 B
    int*    rowptr  = (int*)   (ws + 1201152);      //   400,384 B
    __half* TCh     = (__half*)(ws + 1603584);      //    19,968 B
    float*  pooled  = (float*) (ws + 1623552);      //   262,144 B
    int*    gcur    = (int*)   (ws + 1889792);      //     1,024 B
    int2*   epack   = (int2*)  (ws + 1890816);      // 12,800,000 B
    int*    gbinx   = (int*)   (ws + 14690816);     //  7,340,032 B
    int*    gbiny   = (int*)   (ws + 22030848);     //  7,340,032 B
    __half* h2s     = (__half*)(ws + 29370880);     // 12,800,000 B (total ~42.2 MB)

    hipMemsetAsync(pooled, 0, N_GRAPHS * HID * sizeof(float), stream);
    hipMemsetAsync(gcur, 0, NBUCK * sizeof(int), stream);

    // 1. per-node combo + sorted-batch boundaries (no atomics)
    prep_kernel<<<SCAN_BLOCKS, 256, 0, stream>>>(shape_id, color_id, batch, combo, gstart);

    // 2. combined (shape,color)->h1 table (fp16)
    tc_kernel<<<NCOMBO, 64, 0, stream>>>(st, ct, W1, TCh);

    // 3. bin edges by dst-bucket (split planes)
    binA_kernel<<<(N_EDGES + EPB - 1) / EPB, 512, 0, stream>>>(src, dst, combo, gcur,
                                                               gbinx, gbiny);

    // 4. per-bucket degrees -> dis + rowptr (reads dst plane only; gcur scan folded in)
    bucket_kernel<<<NBUCK, 512, 0, stream>>>(gbiny, gcur, dis, rowptr);

    // 5. per-bucket scatter to CSR (1024 thr)
    binB_kernel<<<NBUCK, 1024, 0, stream>>>(gbinx, gbiny, gcur, rowptr, dis, epack);

    // 6. fused layer-1 aggregate + MFMA mm2 -> h2s (16 nodes/block)
    agg1_mm2_kernel<<<6250, 256, 0, stream>>>(epack, rowptr, combo, dis, TCh, W2, b1, h2s);

    // 7. layer-2 aggregate + pool (paired pipelines, run-merged atomics)
    agg2_pool_kernel<<<6250, 256, 0, stream>>>(epack, rowptr, h2s, dis, b2, batch, pooled);

    // 8. logits (counts from gstart boundaries)
    logits_kernel<<<N_GRAPHS, 64, 0, stream>>>(pooled, gstart, Wl, bl, out);
}

// Round 5
// 196.689 us; speedup vs baseline: 1.0434x; 1.0434x over previous
//
#include <hip/hip_runtime.h>
#include <hip/hip_bf16.h>
#include <hip/hip_fp16.h>

#define N_NODES   100000
#define N_EDGES   1600000
#define N_GRAPHS  1024
#define EMB       32
#define HID       64
#define N_CLASSES 10
#define SCAN_BLOCKS 391   // ceil(100000/256)
#define NCOMBO 153        // 17 shape ids x 9 color ids
#define BUCK_NODES 448    // nodes per dst-bucket
#define NBUCK 224         // ceil(100000/448)
#define BIN_CAP 8192      // per-bucket staging capacity (mean 7143, +12 sigma)
#define EPB 4096          // edges per binA block

typedef _Float16 f16x8 __attribute__((ext_vector_type(8)));
typedef float f32x4 __attribute__((ext_vector_type(4)));

// ---------------- prep: combo[v] + batch boundaries + TC table + buffer zeroing ----------------
// Fuses former tc_kernel (blocks<153, wave 1) and the two memsets (pooled striped,
// gcur block 0) to cut 3 launches.  batch is sorted -> per-graph counts are
// segment boundaries written exactly once (zero atomics).
__global__ __launch_bounds__(256) void prep_kernel(
    const int* __restrict__ sid, const int* __restrict__ cid,
    const int* __restrict__ batch, int* __restrict__ combo, int* __restrict__ gstart,
    const float* __restrict__ st, const float* __restrict__ ct,
    const float* __restrict__ W1, __half* __restrict__ TCh,
    float* __restrict__ pooled, int* __restrict__ gcur) {
    int t = threadIdx.x;
    int v = blockIdx.x * 256 + t;
    // zero pooled (65536 floats striped across the grid) + gcur
    if (v < N_GRAPHS * HID) pooled[v] = 0.0f;
    if (blockIdx.x == 0 && t < NBUCK) gcur[t] = 0;
    if (v < N_NODES) {
        combo[v] = sid[v] * 9 + cid[v];
        int b = batch[v];
        int bp = (v == 0) ? -1 : batch[v - 1];
        for (int g = bp + 1; g <= b; ++g) gstart[g] = v;      // boundary (usually 0 iters)
        if (v == N_NODES - 1) {
            for (int g = b + 1; g <= N_GRAPHS; ++g) gstart[g] = N_NODES;
        }
    }
    // TC table: TCh[s*9+c][j] = (st[s]@W1)[j] + (ct[c]@W1)[j]  (fp16)
    if (blockIdx.x < NCOMBO && t >= 64 && t < 128) {
        int r = blockIdx.x, j = t - 64;
        int s = r / 9, c = r % 9;
        float acc = 0.0f;
        if (s != 0) {
#pragma unroll
            for (int k = 0; k < EMB; ++k) acc = fmaf(st[s * EMB + k], W1[k * HID + j], acc);
        }
        if (c != 0) {
#pragma unroll
            for (int k = 0; k < EMB; ++k) acc = fmaf(ct[c * EMB + k], W1[k * HID + j], acc);
        }
        TCh[r * HID + j] = __float2half_rn(acc);
    }
}

// ---------------- binA: block-local counting sort by dst-bucket, split-plane flush ----------------
__global__ __launch_bounds__(512) void binA_kernel(
    const int* __restrict__ src, const int* __restrict__ dst,
    const int* __restrict__ combo, int* __restrict__ gcur,
    int* __restrict__ gbinx, int* __restrict__ gbiny) {
    __shared__ int2 stg[EPB];            // 32 KB
    __shared__ int hist[NBUCK];
    __shared__ int base[NBUCK + 1];
    __shared__ int gstart[NBUCK];
    __shared__ int scanbuf[256];
    int t = threadIdx.x;
    int e0 = blockIdx.x * EPB;
    for (int i = t; i < NBUCK; i += 512) hist[i] = 0;
    __syncthreads();

    int2 myq[8];
    int mybo[8];
#pragma unroll
    for (int i = 0; i < 8; ++i) {
        int e = e0 + t + i * 512;
        if (e < N_EDGES) {
            int d = dst[e];
            int s = src[e];
            unsigned b = (unsigned)d / BUCK_NODES;
            int off = atomicAdd(&hist[b], 1);
            myq[i].x = s | (combo[s] << 17);
            myq[i].y = d;
            mybo[i] = (int)(b << 16) | off;
        } else {
            mybo[i] = -1;
        }
    }
    __syncthreads();

    int h = (t < NBUCK) ? hist[t] : 0;
    if (t < 256) scanbuf[t] = h;
    __syncthreads();
#pragma unroll
    for (int off = 1; off < 256; off <<= 1) {
        int x = (t < 256 && t >= off) ? scanbuf[t - off] : 0;
        __syncthreads();
        if (t < 256) scanbuf[t] += x;
        __syncthreads();
    }
    if (t < NBUCK) base[t] = scanbuf[t] - h;
    if (t == 0) base[NBUCK] = scanbuf[255];
    __syncthreads();
#pragma unroll
    for (int i = 0; i < 8; ++i) {
        if (mybo[i] >= 0) {
            int b = mybo[i] >> 16, off = mybo[i] & 0xFFFF;
            stg[base[b] + off] = myq[i];
        }
    }
    if (t < NBUCK) {
        int n = hist[t];
        gstart[t] = n ? atomicAdd(&gcur[t], n) : 0;
    }
    __syncthreads();
    int total = base[NBUCK];
    for (int i = t; i < total; i += 512) {
        int2 q = stg[i];
        unsigned b = (unsigned)q.y / BUCK_NODES;
        size_t pos = (size_t)b * BIN_CAP + gstart[b] + (i - base[b]);
        gbinx[pos] = q.x;
        gbiny[pos] = q.y;
    }
}

// ---------------- bucket: per-bucket degrees -> dis + rowptr (dst-plane only; scan folded) ----------------
__global__ __launch_bounds__(512) void bucket_kernel(
    const int* __restrict__ gbiny, const int* __restrict__ gcur,
    float* __restrict__ dis, int* __restrict__ rowptr) {
    __shared__ int ldeg[BUCK_NODES];
    __shared__ int s[512];
    __shared__ int sc[256];
    int b = blockIdx.x, t = threadIdx.x;
    if (t < 256) sc[t] = (t < NBUCK) ? gcur[t] : 0;
    for (int i = t; i < BUCK_NODES; i += 512) ldeg[i] = 0;
    __syncthreads();
    // block-local inclusive scan of gcur (replaces bscan kernel)
#pragma unroll
    for (int off = 1; off < 256; off <<= 1) {
        int x = (t < 256 && t >= off) ? sc[t - off] : 0;
        __syncthreads();
        if (t < 256) sc[t] += x;
        __syncthreads();
    }
    int bb = (b == 0) ? 0 : sc[b - 1];    // exclusive bucket base
    int n = gcur[b];
    const int* mybin = gbiny + (size_t)b * BIN_CAP;
    for (int i = t; i < n; i += 512)
        atomicAdd(&ldeg[mybin[i] - b * BUCK_NODES], 1);
    __syncthreads();
    int d = (t < BUCK_NODES) ? ldeg[t] : 0;
    int v = b * BUCK_NODES + t;
    if (t < BUCK_NODES && v < N_NODES) dis[v] = rsqrtf(1.0f + (float)d);
    s[t] = d;
    __syncthreads();
#pragma unroll
    for (int off = 1; off < 512; off <<= 1) {
        int x = (t >= off) ? s[t - off] : 0;
        __syncthreads();
        s[t] += x;
        __syncthreads();
    }
    if (t < BUCK_NODES && v < N_NODES) rowptr[v] = bb + s[t] - d;
    if (b == 0 && t == 0) rowptr[N_NODES] = N_EDGES;
}

// ---------------- binB: per-bucket fine scatter to CSR (1024 threads) ----------------
// epack.x = (src << 15) | (combo*128)   [src: 17b, combo byte-offset: 15b]
// epack.y = dis[src] as float bits
__global__ __launch_bounds__(1024) void binB_kernel(
    const int* __restrict__ gbinx, const int* __restrict__ gbiny,
    const int* __restrict__ gcur,
    const int* __restrict__ rowptr, const float* __restrict__ dis,
    int2* __restrict__ epack) {
    __shared__ int curs[BUCK_NODES];
    int b = blockIdx.x, t = threadIdx.x;
    for (int i = t; i < BUCK_NODES; i += 1024) curs[i] = 0;
    __syncthreads();
    int n = gcur[b];
    const int* mx = gbinx + (size_t)b * BIN_CAP;
    const int* my = gbiny + (size_t)b * BIN_CAP;
    for (int i = t; i < n; i += 1024) {
        int qx = mx[i];
        int qy = my[i];
        int local = qy - b * BUCK_NODES;
        int r = atomicAdd(&curs[local], 1);
        unsigned sx = (unsigned)qx;
        int srci = (int)(sx & 0x1FFFF);
        int comboOff = (int)((sx >> 17) * 128u);   // <= 19456, fits 15 bits
        int2 rec;
        rec.x = (srci << 15) | comboOff;
        rec.y = __float_as_int(dis[srci]);
        epack[rowptr[qy] + r] = rec;
    }
}

// ---------------- fused layer-1 aggregate + MFMA mm2 ----------------
// Block = 16 consecutive nodes; wave w owns nodes v0..v0+3 for aggregation.
// Edge prefetch: lanes 16n..16n+15 hold edges 0-15 (q1) and 16-31 (q2) of node n.
// Edge consume: readlane broadcast + LDS TC gather.
// mm2: block-cooperative X(16x64,fp16) @ W2(64x64,fp16) via 2x mfma_f32_16x16x32_f16.
#define AGG_CHUNK(Q, LBASE, J0)                                                \
    _Pragma("unroll")                                                          \
    for (int i = 0; i < 8; ++i) {                                              \
        int off = __builtin_amdgcn_readlane((Q).x, (LBASE) + i) & 0x7FFF;      \
        int wb  = __builtin_amdgcn_readlane((Q).y, (LBASE) + i);               \
        off = ((J0) + i < cnt) ? off : 0;                                      \
        wb  = ((J0) + i < cnt) ? wb  : 0;                                      \
        __half tv = *(const __half*)((const char*)TCs + (off + lane2));        \
        acc = fmaf(__int_as_float(wb), __half2float(tv), acc);                 \
    }

#define AGG_NODE(N, RS, RE, DV, CO)                                            \
    {                                                                          \
        int deg = (RE) - (RS);                                                 \
        int cnt = deg > 32 ? 32 : deg;                                         \
        float acc = 0.0f;                                                      \
        AGG_CHUNK(q1, (N)*16, 0)                                               \
        if (cnt > 8)  { AGG_CHUNK(q1, (N)*16 + 8, 8) }                         \
        if (cnt > 16) { AGG_CHUNK(q2, (N)*16, 16) }                            \
        if (cnt > 24) { AGG_CHUNK(q2, (N)*16 + 8, 24) }                        \
        if (deg > 32) {                                                        \
            for (int e = (RS) + 32; e < (RE); ++e) {                           \
                int2 q = epack[e];                                             \
                __half tv = *(const __half*)((const char*)TCs +                \
                                             ((q.x & 0x7FFF) + lane2));        \
                acc = fmaf(__int_as_float(q.y), __half2float(tv), acc);        \
            }                                                                  \
        }                                                                      \
        __half hv = *(const __half*)((const char*)TCs + ((CO) + lane2));       \
        float val = (DV) * fmaf(__half2float(hv), (DV), acc) + bias;           \
        val = val > 0.0f ? val : 0.0f;                                         \
        xsA[w * 4 + (N)][lane] = __float2half_rn(val * (DV));                  \
    }

__global__ __launch_bounds__(256, 6) void agg1_mm2_kernel(
    const int2* __restrict__ epack, const int* __restrict__ rowptr,
    const int* __restrict__ combo, const float* __restrict__ dis,
    const __half* __restrict__ TCh, const float* __restrict__ W2,
    const float* __restrict__ b1, __half* __restrict__ h2s) {
    __shared__ __align__(16) __half TCs[NCOMBO * HID];  // 19,584 B
    __shared__ __align__(16) __half xsA[16][72];        //  2,304 B (stride 72: bank spread)
    __shared__ __align__(16) __half Dst[16 * 64];       //  2,048 B
    int t = threadIdx.x;
    int lane = t & 63, w = t >> 6;
    int lane2 = lane * 2;
    int vb = blockIdx.x * 16;
    int v0 = vb + w * 4;

    // per-lane sliced edge prefetch (longest latency chain - issue first)
    int sub = lane >> 4, sl = lane & 15;
    int rb = rowptr[v0 + sub];
    int2 q1 = epack[rb + sl];        // node sub, edges 0..15
    int2 q2 = epack[rb + 16 + sl];   // node sub, edges 16..31 (may over-read: ok)

    // scalar row pointers
    int r0 = __builtin_amdgcn_readfirstlane(rowptr[v0]);
    int r1 = __builtin_amdgcn_readfirstlane(rowptr[v0 + 1]);
    int r2 = __builtin_amdgcn_readfirstlane(rowptr[v0 + 2]);
    int r3 = __builtin_amdgcn_readfirstlane(rowptr[v0 + 3]);
    int r4 = __builtin_amdgcn_readfirstlane(rowptr[v0 + 4]);

    // per-node epilogue scalars (issue early)
    float d0 = dis[v0], d1 = dis[v0 + 1], d2 = dis[v0 + 2], d3 = dis[v0 + 3];
    int o0 = combo[v0] << 7, o1 = combo[v0 + 1] << 7;
    int o2 = combo[v0 + 2] << 7, o3 = combo[v0 + 3] << 7;
    float bias = b1[lane];

    // B fragments of W2 for this wave's 16 output cols (built once, from global)
    f16x8 bf0, bf1;
    {
        int colw = (w << 4) + (lane & 15);
        int kb = (lane >> 4) * 8;
#pragma unroll
        for (int i = 0; i < 8; ++i) {
            bf0[i] = (_Float16)W2[(kb + i) * HID + colw];
            bf1[i] = (_Float16)W2[(32 + kb + i) * HID + colw];
        }
    }

    // stage TC table to LDS
    {
        const int4* s4 = (const int4*)TCh;
        int4* dd4 = (int4*)TCs;
        for (int i = t; i < NCOMBO * HID * 2 / 16; i += 256) dd4[i] = s4[i];
    }
    __syncthreads();   // also drains the edge prefetch

    AGG_NODE(0, r0, r1, d0, o0)
    AGG_NODE(1, r1, r2, d1, o1)
    AGG_NODE(2, r2, r3, d2, o2)
    AGG_NODE(3, r3, r4, d3, o3)

    __syncthreads();   // all 16 rows of xsA ready

    // A fragments: row = lane&15 (node), k = (lane>>4)*8 + i  (+32 for 2nd MFMA)
    const __half* xa = &xsA[lane & 15][0];
    f16x8 a0 = *(const f16x8*)(xa + (lane >> 4) * 8);
    f16x8 a1 = *(const f16x8*)(xa + 32 + (lane >> 4) * 8);
    f32x4 dacc = {0.0f, 0.0f, 0.0f, 0.0f};
    dacc = __builtin_amdgcn_mfma_f32_16x16x32_f16(a0, bf0, dacc, 0, 0, 0);
    dacc = __builtin_amdgcn_mfma_f32_16x16x32_f16(a1, bf1, dacc, 0, 0, 0);

    // D: col = lane&15 (within wave's 16-col block), row = (lane>>4)*4 + i (node)
    {
        int colg = (w << 4) + (lane & 15);
#pragma unroll
        for (int i = 0; i < 4; ++i)
            Dst[((lane >> 4) * 4 + i) * 64 + colg] = __float2half_rn(dacc[i]);
    }
    __syncthreads();

    // coalesced block store: 16 nodes x 64 feats fp16 = 2048 B contiguous
    {
        const uint2* ds2 = (const uint2*)Dst;
        uint2* go = (uint2*)(h2s + (size_t)vb * HID);
        go[t] = ds2[t];
    }
}

// ---------------- per-node edge accumulate for layer 2 (round-3 proven version) ----------------
// sx: lane i holds epack[rs+i].x.  Broadcast h2s byte-offset per edge via readlane;
// gathers are per-lane vector loads (vmcnt, 8-deep in flight).
__device__ __forceinline__ float agg2_node(const int* __restrict__ epackx, int sx,
                                           int rs, int re, int lane, int lane2,
                                           const __half* __restrict__ h2s) {
    float acc = 0.0f;
    int p = rs;
    for (;;) {
        int avail = re - p;
        int cnt = avail > 64 ? 64 : avail;
        int vo = (int)((((unsigned)sx) >> 15) << 7);   // src*128, vectorized unpack
        int j = 0;
        for (; j + 8 <= cnt; j += 8) {
            float g[8];
#pragma unroll
            for (int i = 0; i < 8; ++i) {
                int off = __builtin_amdgcn_readlane(vo, j + i);
                g[i] = __half2float(*(const __half*)((const char*)h2s + (off + lane2)));
            }
#pragma unroll
            for (int i = 0; i < 8; ++i) acc += g[i];
        }
        if (j < cnt) {
#pragma unroll
            for (int i = 0; i < 8; ++i) {
                int jj = j + i;
                int off = __builtin_amdgcn_readlane(vo, jj & 63);
                float gv = __half2float(*(const __half*)((const char*)h2s + (off + lane2)));
                acc += (jj < cnt) ? gv : 0.0f;
            }
        }
        p += 64;
        if (p >= re) break;
        int idx = p + lane;
        idx = idx < N_EDGES ? idx : N_EDGES - 1;
        sx = epackx[idx * 2];
    }
    return acc;
}

// ---------------- layer-2 aggregate + pool: 4 nodes/wave, run-merged atomics ----------------
__global__ __launch_bounds__(256, 8) void agg2_pool_kernel(
    const int2* __restrict__ epack, const int* __restrict__ rowptr,
    const __half* __restrict__ h2s, const float* __restrict__ dis,
    const float* __restrict__ b2, const int* __restrict__ batch,
    float* __restrict__ pooled) {
    int t = threadIdx.x, lane = t & 63, w = t >> 6;
    int lane2 = lane * 2;
    const int* epackx = (const int*)epack;
    int v0 = (blockIdx.x * 4 + w) * 4;   // grid 6250

    int r0 = __builtin_amdgcn_readfirstlane(rowptr[v0]);
    int r1 = __builtin_amdgcn_readfirstlane(rowptr[v0 + 1]);
    int r2 = __builtin_amdgcn_readfirstlane(rowptr[v0 + 2]);
    int r3 = __builtin_amdgcn_readfirstlane(rowptr[v0 + 3]);
    int r4 = __builtin_amdgcn_readfirstlane(rowptr[v0 + 4]);

    int ia = r0 + lane; ia = ia < N_EDGES ? ia : N_EDGES - 1;
    int ib = r1 + lane; ib = ib < N_EDGES ? ib : N_EDGES - 1;
    int ic = r2 + lane; ic = ic < N_EDGES ? ic : N_EDGES - 1;
    int id = r3 + lane; id = id < N_EDGES ? id : N_EDGES - 1;
    int sa = epackx[ia * 2];
    int sb = epackx[ib * 2];
    int sc = epackx[ic * 2];
    int sd = epackx[id * 2];

    float bv = b2[lane];
    float acc0 = agg2_node(epackx, sa, r0, r1, lane, lane2, h2s);
    float acc1 = agg2_node(epackx, sb, r1, r2, lane, lane2, h2s);
    float acc2 = agg2_node(epackx, sc, r2, r3, lane, lane2, h2s);
    float acc3 = agg2_node(epackx, sd, r3, r4, lane, lane2, h2s);

#define AGG2_VAL(V, ACC, OUT)                                                  \
    {                                                                          \
        float dv = dis[V];                                                     \
        float self = __half2float(h2s[(size_t)(V) * HID + lane]);              \
        float val = dv * ((ACC) + self) + bv;                                  \
        OUT = val > 0.0f ? val : 0.0f;                                         \
    }
    float val0, val1, val2, val3;
    AGG2_VAL(v0, acc0, val0)
    AGG2_VAL(v0 + 1, acc1, val1)
    AGG2_VAL(v0 + 2, acc2, val2)
    AGG2_VAL(v0 + 3, acc3, val3)
#undef AGG2_VAL

    int g0 = __builtin_amdgcn_readfirstlane(batch[v0]);
    int g1 = __builtin_amdgcn_readfirstlane(batch[v0 + 1]);
    int g2 = __builtin_amdgcn_readfirstlane(batch[v0 + 2]);
    int g3 = __builtin_amdgcn_readfirstlane(batch[v0 + 3]);
    // batch is sorted: merge same-graph contributions into one atomic per run
    float s = val0; int g = g0;
    if (g1 == g) { s += val1; } else { unsafeAtomicAdd(&pooled[g * HID + lane], s); g = g1; s = val1; }
    if (g2 == g) { s += val2; } else { unsafeAtomicAdd(&pooled[g * HID + lane], s); g = g2; s = val2; }
    if (g3 == g) { s += val3; } else { unsafeAtomicAdd(&pooled[g * HID + lane], s); g = g3; s = val3; }
    unsafeAtomicAdd(&pooled[g * HID + lane], s);
}

// ---------------- logits ----------------
__global__ __launch_bounds__(64) void logits_kernel(
    const float* __restrict__ pooled, const int* __restrict__ gstart,
    const float* __restrict__ Wl, const float* __restrict__ bl,
    float* __restrict__ out) {
    __shared__ float row[HID];
    int g = blockIdx.x, t = threadIdx.x;
    int c = gstart[g + 1] - gstart[g]; if (c < 1) c = 1;
    row[t] = pooled[g * HID + t] / (float)c;
    __syncthreads();
    if (t < N_CLASSES) {
        float acc = bl[t];
#pragma unroll
        for (int k = 0; k < HID; ++k) acc = fmaf(row[k], Wl[k * N_CLASSES + t], acc);
        out[g * N_CLASSES + t] = acc;
    }
}

extern "C" void kernel_launch(void* const* d_in, const int* in_sizes, int n_in,
                              void* d_out, int out_size, void* d_ws, size_t ws_size,
                              hipStream_t stream) {
    const int*   shape_id = (const int*)d_in[0];
    const int*   color_id = (const int*)d_in[1];
    const int*   edge_idx = (const int*)d_in[2];
    const int*   batch    = (const int*)d_in[3];
    const float* st       = (const float*)d_in[4];
    const float* ct       = (const float*)d_in[5];
    const float* W1       = (const float*)d_in[6];
    const float* b1       = (const float*)d_in[7];
    const float* W2       = (const float*)d_in[8];
    const float* b2       = (const float*)d_in[9];
    const float* Wl       = (const float*)d_in[10];
    const float* bl       = (const float*)d_in[11];
    float* out = (float*)d_out;

    const int* src = edge_idx;
    const int* dst = edge_idx + N_EDGES;

    // workspace layout
    char* ws = (char*)d_ws;
    int*    combo   = (int*)   (ws + 0);            //   400,384 B
    float*  dis     = (float*) (ws + 400384);       //   400,384 B
    int*    gstart  = (int*)   (ws + 801792);       //     4,112 B
    int*    rowptr  = (int*)   (ws + 1201152);      //   400,384 B
    __half* TCh     = (__half*)(ws + 1603584);      //    19,968 B
    float*  pooled  = (float*) (ws + 1623552);      //   262,144 B
    int*    gcur    = (int*)   (ws + 1889792);      //     1,024 B
    int2*   epack   = (int2*)  (ws + 1890816);      // 12,800,000 B
    int*    gbinx   = (int*)   (ws + 14690816);     //  7,340,032 B
    int*    gbiny   = (int*)   (ws + 22030848);     //  7,340,032 B
    __half* h2s     = (__half*)(ws + 29370880);     // 12,800,000 B (total ~42.2 MB)

    // 1. combo + batch boundaries + TC table + pooled/gcur zeroing (fused)
    prep_kernel<<<SCAN_BLOCKS, 256, 0, stream>>>(shape_id, color_id, batch, combo, gstart,
                                                 st, ct, W1, TCh, pooled, gcur);

    // 2. bin edges by dst-bucket (split planes)
    binA_kernel<<<(N_EDGES + EPB - 1) / EPB, 512, 0, stream>>>(src, dst, combo, gcur,
                                                               gbinx, gbiny);

    // 3. per-bucket degrees -> dis + rowptr (reads dst plane only; gcur scan folded in)
    bucket_kernel<<<NBUCK, 512, 0, stream>>>(gbiny, gcur, dis, rowptr);

    // 4. per-bucket scatter to CSR (1024 thr)
    binB_kernel<<<NBUCK, 1024, 0, stream>>>(gbinx, gbiny, gcur, rowptr, dis, epack);

    // 5. fused layer-1 aggregate + MFMA mm2 -> h2s (16 nodes/block)
    agg1_mm2_kernel<<<6250, 256, 0, stream>>>(epack, rowptr, combo, dis, TCh, W2, b1, h2s);

    // 6. layer-2 aggregate + pool (round-3 structure, 8 waves/EU)
    agg2_pool_kernel<<<6250, 256, 0, stream>>>(epack, rowptr, h2s, dis, b2, batch, pooled);

    // 7. logits (counts from gstart boundaries)
    logits_kernel<<<N_GRAPHS, 64, 0, stream>>>(pooled, gstart, Wl, bl, out);
}

// Round 6
// 190.386 us; speedup vs baseline: 1.0780x; 1.0331x over previous
//
#include <hip/hip_runtime.h>
#include <hip/hip_bf16.h>
#include <hip/hip_fp16.h>

#define N_NODES   100000
#define N_EDGES   1600000
#define N_GRAPHS  1024
#define EMB       32
#define HID       64
#define N_CLASSES 10
#define SCAN_BLOCKS 391   // ceil(100000/256)
#define NCOMBO 153        // 17 shape ids x 9 color ids
#define BUCK_NODES 448    // nodes per dst-bucket
#define NBUCK 224         // ceil(100000/448)
#define BIN_CAP 8192      // per-bucket staging capacity (mean 7143, +12 sigma)
#define EPB 4096          // edges per binA block

typedef _Float16 f16x8 __attribute__((ext_vector_type(8)));
typedef float f32x4 __attribute__((ext_vector_type(4)));

// ---------------- prep: combo[v] + batch boundaries + TC table + buffer zeroing ----------------
__global__ __launch_bounds__(256) void prep_kernel(
    const int* __restrict__ sid, const int* __restrict__ cid,
    const int* __restrict__ batch, int* __restrict__ combo, int* __restrict__ gstart,
    const float* __restrict__ st, const float* __restrict__ ct,
    const float* __restrict__ W1, __half* __restrict__ TCh,
    float* __restrict__ pooled, int* __restrict__ gcur) {
    int t = threadIdx.x;
    int v = blockIdx.x * 256 + t;
    if (v < N_GRAPHS * HID) pooled[v] = 0.0f;
    if (blockIdx.x == 0 && t < NBUCK) gcur[t] = 0;
    if (v < N_NODES) {
        combo[v] = sid[v] * 9 + cid[v];
        int b = batch[v];
        int bp = (v == 0) ? -1 : batch[v - 1];
        for (int g = bp + 1; g <= b; ++g) gstart[g] = v;      // boundary (usually 0 iters)
        if (v == N_NODES - 1) {
            for (int g = b + 1; g <= N_GRAPHS; ++g) gstart[g] = N_NODES;
        }
    }
    // TC table: TCh[s*9+c][j] = (st[s]@W1)[j] + (ct[c]@W1)[j]  (fp16)
    if (blockIdx.x < NCOMBO && t >= 64 && t < 128) {
        int r = blockIdx.x, j = t - 64;
        int s = r / 9, c = r % 9;
        float acc = 0.0f;
        if (s != 0) {
#pragma unroll
            for (int k = 0; k < EMB; ++k) acc = fmaf(st[s * EMB + k], W1[k * HID + j], acc);
        }
        if (c != 0) {
#pragma unroll
            for (int k = 0; k < EMB; ++k) acc = fmaf(ct[c * EMB + k], W1[k * HID + j], acc);
        }
        TCh[r * HID + j] = __float2half_rn(acc);
    }
}

// ---------------- binA: block-local counting sort by dst-bucket, split-plane flush ----------------
__global__ __launch_bounds__(512) void binA_kernel(
    const int* __restrict__ src, const int* __restrict__ dst,
    const int* __restrict__ combo, int* __restrict__ gcur,
    int* __restrict__ gbinx, int* __restrict__ gbiny) {
    __shared__ int2 stg[EPB];            // 32 KB
    __shared__ int hist[NBUCK];
    __shared__ int base[NBUCK + 1];
    __shared__ int gstart[NBUCK];
    __shared__ int scanbuf[256];
    int t = threadIdx.x;
    int e0 = blockIdx.x * EPB;
    for (int i = t; i < NBUCK; i += 512) hist[i] = 0;
    __syncthreads();

    int2 myq[8];
    int mybo[8];
#pragma unroll
    for (int i = 0; i < 8; ++i) {
        int e = e0 + t + i * 512;
        if (e < N_EDGES) {
            int d = dst[e];
            int s = src[e];
            unsigned b = (unsigned)d / BUCK_NODES;
            int off = atomicAdd(&hist[b], 1);
            myq[i].x = s | (combo[s] << 17);
            myq[i].y = d;
            mybo[i] = (int)(b << 16) | off;
        } else {
            mybo[i] = -1;
        }
    }
    __syncthreads();

    int h = (t < NBUCK) ? hist[t] : 0;
    if (t < 256) scanbuf[t] = h;
    __syncthreads();
#pragma unroll
    for (int off = 1; off < 256; off <<= 1) {
        int x = (t < 256 && t >= off) ? scanbuf[t - off] : 0;
        __syncthreads();
        if (t < 256) scanbuf[t] += x;
        __syncthreads();
    }
    if (t < NBUCK) base[t] = scanbuf[t] - h;
    if (t == 0) base[NBUCK] = scanbuf[255];
    __syncthreads();
#pragma unroll
    for (int i = 0; i < 8; ++i) {
        if (mybo[i] >= 0) {
            int b = mybo[i] >> 16, off = mybo[i] & 0xFFFF;
            stg[base[b] + off] = myq[i];
        }
    }
    if (t < NBUCK) {
        int n = hist[t];
        gstart[t] = n ? atomicAdd(&gcur[t], n) : 0;
    }
    __syncthreads();
    int total = base[NBUCK];
    for (int i = t; i < total; i += 512) {
        int2 q = stg[i];
        unsigned b = (unsigned)q.y / BUCK_NODES;
        size_t pos = (size_t)b * BIN_CAP + gstart[b] + (i - base[b]);
        gbinx[pos] = q.x;
        gbiny[pos] = q.y;
    }
}

// ---------------- bucket_scatter: degrees + dis + rowptr + CSR scatter (merged) ----------------
// Pass 1: stream gbiny -> LDS stage + degree count.  Scan -> dis/rowptr/rbase.
// Pass 2: stream gbinx, dst from LDS stage, scatter 4B epack records.
// Merge enabled by epack no longer carrying dis[src] (agg1 gathers dis per-lane).
// epack4[e] = (src << 15) | (combo*128)
__global__ __launch_bounds__(1024) void bucket_scatter_kernel(
    const int* __restrict__ gbinx, const int* __restrict__ gbiny,
    const int* __restrict__ gcur,
    float* __restrict__ dis, int* __restrict__ rowptr, int* __restrict__ epack4) {
    __shared__ int ybin[BIN_CAP];        // 32 KB: staged dst plane
    __shared__ int ldeg[BUCK_NODES];     // degree count, then scatter cursors
    __shared__ int rbase[BUCK_NODES];    // per-node CSR base
    __shared__ int s[512];
    __shared__ int sc[256];
    int b = blockIdx.x, t = threadIdx.x;
    if (t < 256) sc[t] = (t < NBUCK) ? gcur[t] : 0;
    for (int i = t; i < BUCK_NODES; i += 1024) ldeg[i] = 0;
    __syncthreads();
    // inclusive scan of gcur -> bucket base
#pragma unroll
    for (int off = 1; off < 256; off <<= 1) {
        int x = (t < 256 && t >= off) ? sc[t - off] : 0;
        __syncthreads();
        if (t < 256) sc[t] += x;
        __syncthreads();
    }
    int bb = (b == 0) ? 0 : sc[b - 1];
    int n = gcur[b];
    // pass 1: stage dst + count degrees
    {
        const int* my = gbiny + (size_t)b * BIN_CAP;
        for (int i = t; i < n; i += 1024) {
            int y = my[i];
            ybin[i] = y;
            atomicAdd(&ldeg[y - b * BUCK_NODES], 1);
        }
    }
    __syncthreads();
    int d = (t < BUCK_NODES) ? ldeg[t] : 0;
    int v = b * BUCK_NODES + t;
    if (t < BUCK_NODES && v < N_NODES) dis[v] = rsqrtf(1.0f + (float)d);
    if (t < 512) s[t] = d;
    __syncthreads();
#pragma unroll
    for (int off = 1; off < 512; off <<= 1) {
        int x = (t < 512 && t >= off) ? s[t - off] : 0;
        __syncthreads();
        if (t < 512) s[t] += x;
        __syncthreads();
    }
    if (t < BUCK_NODES) {
        int rp = bb + s[t] - d;
        rbase[t] = rp;
        if (v < N_NODES) rowptr[v] = rp;
    }
    if (b == 0 && t == 0) rowptr[N_NODES] = N_EDGES;
    // reset cursors
    for (int i = t; i < BUCK_NODES; i += 1024) ldeg[i] = 0;
    __syncthreads();
    // pass 2: scatter
    {
        const int* mx = gbinx + (size_t)b * BIN_CAP;
        for (int i = t; i < n; i += 1024) {
            int qx = mx[i];
            int local = ybin[i] - b * BUCK_NODES;
            int r = atomicAdd(&ldeg[local], 1);
            unsigned sx = (unsigned)qx;
            int srci = (int)(sx & 0x1FFFF);
            int comboOff = (int)((sx >> 17) * 128u);   // <= 19456, fits 15 bits
            epack4[rbase[local] + r] = (srci << 15) | comboOff;
        }
    }
}

// ---------------- fused layer-1 aggregate + MFMA mm2 ----------------
// Block = 16 consecutive nodes; wave w owns nodes v0..v0+3 for aggregation.
// Edge prefetch: lanes 16n..16n+15 hold edge words 0-15 (q1x) and 16-31 (q2x) of
// node n; dis[src] gathered per-lane (L2-resident 400KB) right behind it.
// Edge consume: readlane broadcast of offset+weight + LDS TC gather.
// mm2: block-cooperative X(16x64,fp16) @ W2(64x64,fp16) via 2x mfma_f32_16x16x32_f16.
#define AGG_CHUNK(QX, DQ, LBASE, J0)                                           \
    _Pragma("unroll")                                                          \
    for (int i = 0; i < 8; ++i) {                                              \
        int off = __builtin_amdgcn_readlane((QX), (LBASE) + i) & 0x7FFF;       \
        int wb  = __builtin_amdgcn_readlane(__float_as_int(DQ), (LBASE) + i);  \
        off = ((J0) + i < cnt) ? off : 0;                                      \
        wb  = ((J0) + i < cnt) ? wb  : 0;                                      \
        __half tv = *(const __half*)((const char*)TCs + (off + lane2));        \
        acc = fmaf(__int_as_float(wb), __half2float(tv), acc);                 \
    }

#define AGG_NODE(N, RS, RE, DV, CO)                                            \
    {                                                                          \
        int deg = (RE) - (RS);                                                 \
        int cnt = deg > 32 ? 32 : deg;                                         \
        float acc = 0.0f;                                                      \
        AGG_CHUNK(q1x, dq1, (N)*16, 0)                                         \
        if (cnt > 8)  { AGG_CHUNK(q1x, dq1, (N)*16 + 8, 8) }                   \
        if (cnt > 16) { AGG_CHUNK(q2x, dq2, (N)*16, 16) }                      \
        if (cnt > 24) { AGG_CHUNK(q2x, dq2, (N)*16 + 8, 24) }                  \
        if (deg > 32) {                                                        \
            for (int e = (RS) + 32; e < (RE); ++e) {                           \
                int qx = epack4[e];                                            \
                float dw = dis[(unsigned)qx >> 15];                            \
                __half tv = *(const __half*)((const char*)TCs +                \
                                             ((qx & 0x7FFF) + lane2));         \
                acc = fmaf(dw, __half2float(tv), acc);                         \
            }                                                                  \
        }                                                                      \
        __half hv = *(const __half*)((const char*)TCs + ((CO) + lane2));       \
        float val = (DV) * fmaf(__half2float(hv), (DV), acc) + bias;           \
        val = val > 0.0f ? val : 0.0f;                                         \
        xsA[w * 4 + (N)][lane] = __float2half_rn(val * (DV));                  \
    }

__global__ __launch_bounds__(256, 6) void agg1_mm2_kernel(
    const int* __restrict__ epack4, const int* __restrict__ rowptr,
    const int* __restrict__ combo, const float* __restrict__ dis,
    const __half* __restrict__ TCh, const float* __restrict__ W2,
    const float* __restrict__ b1, __half* __restrict__ h2s) {
    __shared__ __align__(16) __half TCs[NCOMBO * HID];  // 19,584 B
    __shared__ __align__(16) __half xsA[16][72];        //  2,304 B (stride 72: bank spread)
    __shared__ __align__(16) __half Dst[16 * 64];       //  2,048 B
    int t = threadIdx.x;
    int lane = t & 63, w = t >> 6;
    int lane2 = lane * 2;
    int vb = blockIdx.x * 16;
    int v0 = vb + w * 4;

    // per-lane sliced edge prefetch (longest latency chain - issue first)
    int sub = lane >> 4, sl = lane & 15;
    int rb = rowptr[v0 + sub];
    int q1x = epack4[rb + sl];        // node sub, edges 0..15
    int q2x = epack4[rb + 16 + sl];   // node sub, edges 16..31 (may over-read: ok, ws continues)
    float dq1 = dis[(unsigned)q1x >> 15];   // dependent gather, L2-resident
    float dq2 = dis[(unsigned)q2x >> 15];

    // scalar row pointers
    int r0 = __builtin_amdgcn_readfirstlane(rowptr[v0]);
    int r1 = __builtin_amdgcn_readfirstlane(rowptr[v0 + 1]);
    int r2 = __builtin_amdgcn_readfirstlane(rowptr[v0 + 2]);
    int r3 = __builtin_amdgcn_readfirstlane(rowptr[v0 + 3]);
    int r4 = __builtin_amdgcn_readfirstlane(rowptr[v0 + 4]);

    // per-node epilogue scalars (issue early)
    float d0 = dis[v0], d1 = dis[v0 + 1], d2 = dis[v0 + 2], d3 = dis[v0 + 3];
    int o0 = combo[v0] << 7, o1 = combo[v0 + 1] << 7;
    int o2 = combo[v0 + 2] << 7, o3 = combo[v0 + 3] << 7;
    float bias = b1[lane];

    // B fragments of W2 for this wave's 16 output cols (built once, from global)
    f16x8 bf0, bf1;
    {
        int colw = (w << 4) + (lane & 15);
        int kb = (lane >> 4) * 8;
#pragma unroll
        for (int i = 0; i < 8; ++i) {
            bf0[i] = (_Float16)W2[(kb + i) * HID + colw];
            bf1[i] = (_Float16)W2[(32 + kb + i) * HID + colw];
        }
    }

    // stage TC table to LDS
    {
        const int4* s4 = (const int4*)TCh;
        int4* dd4 = (int4*)TCs;
        for (int i = t; i < NCOMBO * HID * 2 / 16; i += 256) dd4[i] = s4[i];
    }
    __syncthreads();   // also drains the edge + dis prefetch

    AGG_NODE(0, r0, r1, d0, o0)
    AGG_NODE(1, r1, r2, d1, o1)
    AGG_NODE(2, r2, r3, d2, o2)
    AGG_NODE(3, r3, r4, d3, o3)

    __syncthreads();   // all 16 rows of xsA ready

    // A fragments: row = lane&15 (node), k = (lane>>4)*8 + i  (+32 for 2nd MFMA)
    const __half* xa = &xsA[lane & 15][0];
    f16x8 a0 = *(const f16x8*)(xa + (lane >> 4) * 8);
    f16x8 a1 = *(const f16x8*)(xa + 32 + (lane >> 4) * 8);
    f32x4 dacc = {0.0f, 0.0f, 0.0f, 0.0f};
    dacc = __builtin_amdgcn_mfma_f32_16x16x32_f16(a0, bf0, dacc, 0, 0, 0);
    dacc = __builtin_amdgcn_mfma_f32_16x16x32_f16(a1, bf1, dacc, 0, 0, 0);

    // D: col = lane&15 (within wave's 16-col block), row = (lane>>4)*4 + i (node)
    {
        int colg = (w << 4) + (lane & 15);
#pragma unroll
        for (int i = 0; i < 4; ++i)
            Dst[((lane >> 4) * 4 + i) * 64 + colg] = __float2half_rn(dacc[i]);
    }
    __syncthreads();

    // coalesced block store: 16 nodes x 64 feats fp16 = 2048 B contiguous
    {
        const uint2* ds2 = (const uint2*)Dst;
        uint2* go = (uint2*)(h2s + (size_t)vb * HID);
        go[t] = ds2[t];
    }
}

// ---------------- per-node edge accumulate for layer 2 ----------------
// sx: lane i holds epack4[rs+i] (dense 4B).  Broadcast h2s byte-offset per edge
// via readlane; gathers are per-lane vector loads (vmcnt, 8-deep in flight).
__device__ __forceinline__ float agg2_node(const int* __restrict__ epack4, int sx,
                                           int rs, int re, int lane, int lane2,
                                           const __half* __restrict__ h2s) {
    float acc = 0.0f;
    int p = rs;
    for (;;) {
        int avail = re - p;
        int cnt = avail > 64 ? 64 : avail;
        int vo = (int)((((unsigned)sx) >> 15) << 7);   // src*128, vectorized unpack
        int j = 0;
        for (; j + 8 <= cnt; j += 8) {
            float g[8];
#pragma unroll
            for (int i = 0; i < 8; ++i) {
                int off = __builtin_amdgcn_readlane(vo, j + i);
                g[i] = __half2float(*(const __half*)((const char*)h2s + (off + lane2)));
            }
#pragma unroll
            for (int i = 0; i < 8; ++i) acc += g[i];
        }
        if (j < cnt) {
#pragma unroll
            for (int i = 0; i < 8; ++i) {
                int jj = j + i;
                int off = __builtin_amdgcn_readlane(vo, jj & 63);
                float gv = __half2float(*(const __half*)((const char*)h2s + (off + lane2)));
                acc += (jj < cnt) ? gv : 0.0f;
            }
        }
        p += 64;
        if (p >= re) break;
        int idx = p + lane;
        idx = idx < N_EDGES ? idx : N_EDGES - 1;
        sx = epack4[idx];
    }
    return acc;
}

// ---------------- layer-2 aggregate + pool: 4 nodes/wave, run-merged atomics ----------------
__global__ __launch_bounds__(256, 8) void agg2_pool_kernel(
    const int* __restrict__ epack4, const int* __restrict__ rowptr,
    const __half* __restrict__ h2s, const float* __restrict__ dis,
    const float* __restrict__ b2, const int* __restrict__ batch,
    float* __restrict__ pooled) {
    int t = threadIdx.x, lane = t & 63, w = t >> 6;
    int lane2 = lane * 2;
    int v0 = (blockIdx.x * 4 + w) * 4;   // grid 6250

    int r0 = __builtin_amdgcn_readfirstlane(rowptr[v0]);
    int r1 = __builtin_amdgcn_readfirstlane(rowptr[v0 + 1]);
    int r2 = __builtin_amdgcn_readfirstlane(rowptr[v0 + 2]);
    int r3 = __builtin_amdgcn_readfirstlane(rowptr[v0 + 3]);
    int r4 = __builtin_amdgcn_readfirstlane(rowptr[v0 + 4]);

    int ia = r0 + lane; ia = ia < N_EDGES ? ia : N_EDGES - 1;
    int ib = r1 + lane; ib = ib < N_EDGES ? ib : N_EDGES - 1;
    int ic = r2 + lane; ic = ic < N_EDGES ? ic : N_EDGES - 1;
    int id = r3 + lane; id = id < N_EDGES ? id : N_EDGES - 1;
    int sa = epack4[ia];
    int sb = epack4[ib];
    int sc = epack4[ic];
    int sd = epack4[id];

    float bv = b2[lane];
    float acc0 = agg2_node(epack4, sa, r0, r1, lane, lane2, h2s);
    float acc1 = agg2_node(epack4, sb, r1, r2, lane, lane2, h2s);
    float acc2 = agg2_node(epack4, sc, r2, r3, lane, lane2, h2s);
    float acc3 = agg2_node(epack4, sd, r3, r4, lane, lane2, h2s);

#define AGG2_VAL(V, ACC, OUT)                                                  \
    {                                                                          \
        float dv = dis[V];                                                     \
        float self = __half2float(h2s[(size_t)(V) * HID + lane]);              \
        float val = dv * ((ACC) + self) + bv;                                  \
        OUT = val > 0.0f ? val : 0.0f;                                         \
    }
    float val0, val1, val2, val3;
    AGG2_VAL(v0, acc0, val0)
    AGG2_VAL(v0 + 1, acc1, val1)
    AGG2_VAL(v0 + 2, acc2, val2)
    AGG2_VAL(v0 + 3, acc3, val3)
#undef AGG2_VAL

    int g0 = __builtin_amdgcn_readfirstlane(batch[v0]);
    int g1 = __builtin_amdgcn_readfirstlane(batch[v0 + 1]);
    int g2 = __builtin_amdgcn_readfirstlane(batch[v0 + 2]);
    int g3 = __builtin_amdgcn_readfirstlane(batch[v0 + 3]);
    // batch is sorted: merge same-graph contributions into one atomic per run
    float s = val0; int g = g0;
    if (g1 == g) { s += val1; } else { unsafeAtomicAdd(&pooled[g * HID + lane], s); g = g1; s = val1; }
    if (g2 == g) { s += val2; } else { unsafeAtomicAdd(&pooled[g * HID + lane], s); g = g2; s = val2; }
    if (g3 == g) { s += val3; } else { unsafeAtomicAdd(&pooled[g * HID + lane], s); g = g3; s = val3; }
    unsafeAtomicAdd(&pooled[g * HID + lane], s);
}

// ---------------- logits ----------------
__global__ __launch_bounds__(64) void logits_kernel(
    const float* __restrict__ pooled, const int* __restrict__ gstart,
    const float* __restrict__ Wl, const float* __restrict__ bl,
    float* __restrict__ out) {
    __shared__ float row[HID];
    int g = blockIdx.x, t = threadIdx.x;
    int c = gstart[g + 1] - gstart[g]; if (c < 1) c = 1;
    row[t] = pooled[g * HID + t] / (float)c;
    __syncthreads();
    if (t < N_CLASSES) {
        float acc = bl[t];
#pragma unroll
        for (int k = 0; k < HID; ++k) acc = fmaf(row[k], Wl[k * N_CLASSES + t], acc);
        out[g * N_CLASSES + t] = acc;
    }
}

extern "C" void kernel_launch(void* const* d_in, const int* in_sizes, int n_in,
                              void* d_out, int out_size, void* d_ws, size_t ws_size,
                              hipStream_t stream) {
    const int*   shape_id = (const int*)d_in[0];
    const int*   color_id = (const int*)d_in[1];
    const int*   edge_idx = (const int*)d_in[2];
    const int*   batch    = (const int*)d_in[3];
    const float* st       = (const float*)d_in[4];
    const float* ct       = (const float*)d_in[5];
    const float* W1       = (const float*)d_in[6];
    const float* b1       = (const float*)d_in[7];
    const float* W2       = (const float*)d_in[8];
    const float* b2       = (const float*)d_in[9];
    const float* Wl       = (const float*)d_in[10];
    const float* bl       = (const float*)d_in[11];
    float* out = (float*)d_out;

    const int* src = edge_idx;
    const int* dst = edge_idx + N_EDGES;

    // workspace layout
    char* ws = (char*)d_ws;
    int*    combo   = (int*)   (ws + 0);            //   400,384 B
    float*  dis     = (float*) (ws + 400384);       //   400,384 B
    int*    gstart  = (int*)   (ws + 801792);       //     4,112 B
    int*    rowptr  = (int*)   (ws + 1201152);      //   400,384 B
    __half* TCh     = (__half*)(ws + 1603584);      //    19,968 B
    float*  pooled  = (float*) (ws + 1623552);      //   262,144 B
    int*    gcur    = (int*)   (ws + 1889792);      //     1,024 B
    int*    epack4  = (int*)   (ws + 1890816);      //  6,400,000 B (4B/edge)
    int*    gbinx   = (int*)   (ws + 14690816);     //  7,340,032 B
    int*    gbiny   = (int*)   (ws + 22030848);     //  7,340,032 B
    __half* h2s     = (__half*)(ws + 29370880);     // 12,800,000 B (total ~42.2 MB)

    // 1. combo + batch boundaries + TC table + pooled/gcur zeroing (fused)
    prep_kernel<<<SCAN_BLOCKS, 256, 0, stream>>>(shape_id, color_id, batch, combo, gstart,
                                                 st, ct, W1, TCh, pooled, gcur);

    // 2. bin edges by dst-bucket (split planes)
    binA_kernel<<<(N_EDGES + EPB - 1) / EPB, 512, 0, stream>>>(src, dst, combo, gcur,
                                                               gbinx, gbiny);

    // 3. merged: degrees + dis + rowptr + CSR scatter (gbiny staged in LDS, read once)
    bucket_scatter_kernel<<<NBUCK, 1024, 0, stream>>>(gbinx, gbiny, gcur,
                                                      dis, rowptr, epack4);

    // 4. fused layer-1 aggregate + MFMA mm2 -> h2s (16 nodes/block)
    agg1_mm2_kernel<<<6250, 256, 0, stream>>>(epack4, rowptr, combo, dis, TCh, W2, b1, h2s);

    // 5. layer-2 aggregate + pool (8 waves/EU, dense 4B edge reads)
    agg2_pool_kernel<<<6250, 256, 0, stream>>>(epack4, rowptr, h2s, dis, b2, batch, pooled);

    // 6. logits (counts from gstart boundaries)
    logits_kernel<<<N_GRAPHS, 64, 0, stream>>>(pooled, gstart, Wl, bl, out);
}

// Round 7
// 188.799 us; speedup vs baseline: 1.0870x; 1.0084x over previous
//
#include <hip/hip_runtime.h>
#include <hip/hip_bf16.h>
#include <hip/hip_fp16.h>

#define N_NODES   100000
#define N_EDGES   1600000
#define N_GRAPHS  1024
#define EMB       32
#define HID       64
#define N_CLASSES 10
#define SCAN_BLOCKS 391   // ceil(100000/256)
#define NCOMBO 153        // 17 shape ids x 9 color ids
#define BUCK_NODES 448    // nodes per dst-bucket
#define NBUCK 224         // ceil(100000/448)
#define BIN_CAP 8192      // per-bucket staging capacity (mean 7143, +12 sigma)
#define EPB 4096          // edges per binA block

typedef _Float16 f16x8 __attribute__((ext_vector_type(8)));
typedef float f32x4 __attribute__((ext_vector_type(4)));

// ---------------- prep: combo[v] + batch boundaries + TC table + buffer zeroing ----------------
__global__ __launch_bounds__(256) void prep_kernel(
    const int* __restrict__ sid, const int* __restrict__ cid,
    const int* __restrict__ batch, int* __restrict__ combo, int* __restrict__ gstart,
    const float* __restrict__ st, const float* __restrict__ ct,
    const float* __restrict__ W1, __half* __restrict__ TCh,
    float* __restrict__ pooled, int* __restrict__ gcur) {
    int t = threadIdx.x;
    int v = blockIdx.x * 256 + t;
    if (v < N_GRAPHS * HID) pooled[v] = 0.0f;
    if (blockIdx.x == 0 && t < NBUCK) gcur[t] = 0;
    if (v < N_NODES) {
        combo[v] = sid[v] * 9 + cid[v];
        int b = batch[v];
        int bp = (v == 0) ? -1 : batch[v - 1];
        for (int g = bp + 1; g <= b; ++g) gstart[g] = v;      // boundary (usually 0 iters)
        if (v == N_NODES - 1) {
            for (int g = b + 1; g <= N_GRAPHS; ++g) gstart[g] = N_NODES;
        }
    }
    // TC table: TCh[s*9+c][j] = (st[s]@W1)[j] + (ct[c]@W1)[j]  (fp16)
    if (blockIdx.x < NCOMBO && t >= 64 && t < 128) {
        int r = blockIdx.x, j = t - 64;
        int s = r / 9, c = r % 9;
        float acc = 0.0f;
        if (s != 0) {
#pragma unroll
            for (int k = 0; k < EMB; ++k) acc = fmaf(st[s * EMB + k], W1[k * HID + j], acc);
        }
        if (c != 0) {
#pragma unroll
            for (int k = 0; k < EMB; ++k) acc = fmaf(ct[c * EMB + k], W1[k * HID + j], acc);
        }
        TCh[r * HID + j] = __float2half_rn(acc);
    }
}

// ---------------- binA: block-local counting sort by dst-bucket, split-plane flush ----------------
// Raw (src,dst) only - no combo gather (agg1 gathers combo per-lane later).
// Edge loads vectorized: 8 consecutive edges/thread via 4x int4 (dense 1KB/wave-instr).
__global__ __launch_bounds__(512) void binA_kernel(
    const int* __restrict__ src, const int* __restrict__ dst,
    int* __restrict__ gcur,
    int* __restrict__ gbinx, int* __restrict__ gbiny) {
    __shared__ int2 stg[EPB];            // 32 KB
    __shared__ int hist[NBUCK];
    __shared__ int base[NBUCK + 1];
    __shared__ int gstart[NBUCK];
    __shared__ int scanbuf[256];
    int t = threadIdx.x;
    int e0 = blockIdx.x * EPB;
    for (int i = t; i < NBUCK; i += 512) hist[i] = 0;
    __syncthreads();

    int2 myq[8];
    int mybo[8];
    if (e0 + EPB <= N_EDGES) {
        int eb = e0 + t * 8;
        int4 sa4 = *(const int4*)&src[eb];
        int4 sb4 = *(const int4*)&src[eb + 4];
        int4 da4 = *(const int4*)&dst[eb];
        int4 db4 = *(const int4*)&dst[eb + 4];
        int ss[8] = {sa4.x, sa4.y, sa4.z, sa4.w, sb4.x, sb4.y, sb4.z, sb4.w};
        int dd[8] = {da4.x, da4.y, da4.z, da4.w, db4.x, db4.y, db4.z, db4.w};
#pragma unroll
        for (int i = 0; i < 8; ++i) {
            unsigned b = (unsigned)dd[i] / BUCK_NODES;
            int off = atomicAdd(&hist[b], 1);
            myq[i].x = ss[i];
            myq[i].y = dd[i];
            mybo[i] = (int)(b << 16) | off;
        }
    } else {
#pragma unroll
        for (int i = 0; i < 8; ++i) {
            int e = e0 + t * 8 + i;
            if (e < N_EDGES) {
                int d = dst[e];
                unsigned b = (unsigned)d / BUCK_NODES;
                int off = atomicAdd(&hist[b], 1);
                myq[i].x = src[e];
                myq[i].y = d;
                mybo[i] = (int)(b << 16) | off;
            } else {
                mybo[i] = -1;
            }
        }
    }
    __syncthreads();

    int h = (t < NBUCK) ? hist[t] : 0;
    if (t < 256) scanbuf[t] = h;
    __syncthreads();
#pragma unroll
    for (int off = 1; off < 256; off <<= 1) {
        int x = (t < 256 && t >= off) ? scanbuf[t - off] : 0;
        __syncthreads();
        if (t < 256) scanbuf[t] += x;
        __syncthreads();
    }
    if (t < NBUCK) base[t] = scanbuf[t] - h;
    if (t == 0) base[NBUCK] = scanbuf[255];
    __syncthreads();
#pragma unroll
    for (int i = 0; i < 8; ++i) {
        if (mybo[i] >= 0) {
            int b = mybo[i] >> 16, off = mybo[i] & 0xFFFF;
            stg[base[b] + off] = myq[i];
        }
    }
    if (t < NBUCK) {
        int n = hist[t];
        gstart[t] = n ? atomicAdd(&gcur[t], n) : 0;
    }
    __syncthreads();
    int total = base[NBUCK];
    for (int i = t; i < total; i += 512) {
        int2 q = stg[i];
        unsigned b = (unsigned)q.y / BUCK_NODES;
        size_t pos = (size_t)b * BIN_CAP + gstart[b] + (i - base[b]);
        gbinx[pos] = q.x;
        gbiny[pos] = q.y;
    }
}

// ---------------- bucket_scatter: degrees + dis + rowptr + CSR scatter (merged) ----------------
// Pass 1: stream gbiny (int4) -> LDS stage + degree count.  Scan -> dis/rowptr/rbase.
// Pass 2: stream gbinx (int4), dst from LDS stage, scatter plain-src epack records.
// epack4[e] = src
__global__ __launch_bounds__(1024) void bucket_scatter_kernel(
    const int* __restrict__ gbinx, const int* __restrict__ gbiny,
    const int* __restrict__ gcur,
    float* __restrict__ dis, int* __restrict__ rowptr, int* __restrict__ epack4) {
    __shared__ __align__(16) int ybin[BIN_CAP];   // 32 KB: staged dst plane
    __shared__ int ldeg[BUCK_NODES];              // degree count, then scatter cursors
    __shared__ int rbase[BUCK_NODES];             // per-node CSR base
    __shared__ int s[512];
    __shared__ int sc[256];
    int b = blockIdx.x, t = threadIdx.x;
    if (t < 256) sc[t] = (t < NBUCK) ? gcur[t] : 0;
    for (int i = t; i < BUCK_NODES; i += 1024) ldeg[i] = 0;
    __syncthreads();
    // inclusive scan of gcur -> bucket base
#pragma unroll
    for (int off = 1; off < 256; off <<= 1) {
        int x = (t < 256 && t >= off) ? sc[t - off] : 0;
        __syncthreads();
        if (t < 256) sc[t] += x;
        __syncthreads();
    }
    int bb = (b == 0) ? 0 : sc[b - 1];
    int n = gcur[b];
    int nc = (n + 3) >> 2;
    // pass 1: stage dst + count degrees (int4 streams)
    {
        const int4* my4 = (const int4*)(gbiny + (size_t)b * BIN_CAP);
        for (int c = t; c < nc; c += 1024) {
            int4 y4 = my4[c];
            ((int4*)ybin)[c] = y4;
            int i0 = c * 4;
            if (i0 + 0 < n) atomicAdd(&ldeg[y4.x - b * BUCK_NODES], 1);
            if (i0 + 1 < n) atomicAdd(&ldeg[y4.y - b * BUCK_NODES], 1);
            if (i0 + 2 < n) atomicAdd(&ldeg[y4.z - b * BUCK_NODES], 1);
            if (i0 + 3 < n) atomicAdd(&ldeg[y4.w - b * BUCK_NODES], 1);
        }
    }
    __syncthreads();
    int d = (t < BUCK_NODES) ? ldeg[t] : 0;
    int v = b * BUCK_NODES + t;
    if (t < BUCK_NODES && v < N_NODES) dis[v] = rsqrtf(1.0f + (float)d);
    if (t < 512) s[t] = d;
    __syncthreads();
#pragma unroll
    for (int off = 1; off < 512; off <<= 1) {
        int x = (t < 512 && t >= off) ? s[t - off] : 0;
        __syncthreads();
        if (t < 512) s[t] += x;
        __syncthreads();
    }
    if (t < BUCK_NODES) {
        int rp = bb + s[t] - d;
        rbase[t] = rp;
        if (v < N_NODES) rowptr[v] = rp;
    }
    if (b == 0 && t == 0) rowptr[N_NODES] = N_EDGES;
    // reset cursors
    for (int i = t; i < BUCK_NODES; i += 1024) ldeg[i] = 0;
    __syncthreads();
    // pass 2: scatter (int4 src stream)
    {
        const int4* mx4 = (const int4*)(gbinx + (size_t)b * BIN_CAP);
        for (int c = t; c < nc; c += 1024) {
            int4 x4 = mx4[c];
            int i0 = c * 4;
            if (i0 + 0 < n) {
                int local = ybin[i0 + 0] - b * BUCK_NODES;
                int r = atomicAdd(&ldeg[local], 1);
                epack4[rbase[local] + r] = x4.x;
            }
            if (i0 + 1 < n) {
                int local = ybin[i0 + 1] - b * BUCK_NODES;
                int r = atomicAdd(&ldeg[local], 1);
                epack4[rbase[local] + r] = x4.y;
            }
            if (i0 + 2 < n) {
                int local = ybin[i0 + 2] - b * BUCK_NODES;
                int r = atomicAdd(&ldeg[local], 1);
                epack4[rbase[local] + r] = x4.z;
            }
            if (i0 + 3 < n) {
                int local = ybin[i0 + 3] - b * BUCK_NODES;
                int r = atomicAdd(&ldeg[local], 1);
                epack4[rbase[local] + r] = x4.w;
            }
        }
    }
}

// ---------------- fused layer-1 aggregate + MFMA mm2 ----------------
// Block = 16 consecutive nodes; wave w owns nodes v0..v0+3 for aggregation.
// Edge prefetch: lanes 16n..16n+15 hold src words 0-15 (q1x) and 16-31 (q2x) of
// node n; dis[src] and combo[src]<<7 gathered per-lane (both L2-resident).
// Edge consume: readlane broadcast of TC offset + weight, LDS TC gather.
// mm2: block-cooperative X(16x64,fp16) @ W2(64x64,fp16) via 2x mfma_f32_16x16x32_f16.
#define AGG_CHUNK(CQ, DQ, LBASE, J0)                                           \
    _Pragma("unroll")                                                          \
    for (int i = 0; i < 8; ++i) {                                              \
        int off = __builtin_amdgcn_readlane((CQ), (LBASE) + i) & 0x7FFF;       \
        int wb  = __builtin_amdgcn_readlane(__float_as_int(DQ), (LBASE) + i);  \
        off = ((J0) + i < cnt) ? off : 0;                                      \
        wb  = ((J0) + i < cnt) ? wb  : 0;                                      \
        __half tv = *(const __half*)((const char*)TCs + (off + lane2));        \
        acc = fmaf(__int_as_float(wb), __half2float(tv), acc);                 \
    }

#define AGG_NODE(N, RS, RE, DV, CO)                                            \
    {                                                                          \
        int deg = (RE) - (RS);                                                 \
        int cnt = deg > 32 ? 32 : deg;                                         \
        float acc = 0.0f;                                                      \
        AGG_CHUNK(cq1, dq1, (N)*16, 0)                                         \
        if (cnt > 8)  { AGG_CHUNK(cq1, dq1, (N)*16 + 8, 8) }                   \
        if (cnt > 16) { AGG_CHUNK(cq2, dq2, (N)*16, 16) }                      \
        if (cnt > 24) { AGG_CHUNK(cq2, dq2, (N)*16 + 8, 24) }                  \
        if (deg > 32) {                                                        \
            for (int e = (RS) + 32; e < (RE); ++e) {                           \
                int qx = epack4[e];                                            \
                float dw = dis[qx];                                            \
                __half tv = *(const __half*)((const char*)TCs +                \
                                             ((combo[qx] << 7) + lane2));      \
                acc = fmaf(dw, __half2float(tv), acc);                         \
            }                                                                  \
        }                                                                      \
        __half hv = *(const __half*)((const char*)TCs + ((CO) + lane2));       \
        float val = (DV) * fmaf(__half2float(hv), (DV), acc) + bias;           \
        val = val > 0.0f ? val : 0.0f;                                         \
        xsA[w * 4 + (N)][lane] = __float2half_rn(val * (DV));                  \
    }

__global__ __launch_bounds__(256, 6) void agg1_mm2_kernel(
    const int* __restrict__ epack4, const int* __restrict__ rowptr,
    const int* __restrict__ combo, const float* __restrict__ dis,
    const __half* __restrict__ TCh, const float* __restrict__ W2,
    const float* __restrict__ b1, __half* __restrict__ h2s) {
    __shared__ __align__(16) __half TCs[NCOMBO * HID];  // 19,584 B
    __shared__ __align__(16) __half xsA[16][72];        //  2,304 B (stride 72: bank spread)
    __shared__ __align__(16) __half Dst[16 * 64];       //  2,048 B
    int t = threadIdx.x;
    int lane = t & 63, w = t >> 6;
    int lane2 = lane * 2;
    int vb = blockIdx.x * 16;
    int v0 = vb + w * 4;

    // per-lane sliced edge prefetch (longest latency chain - issue first)
    int sub = lane >> 4, sl = lane & 15;
    int rb = rowptr[v0 + sub];
    int q1x = epack4[rb + sl] & 0x1FFFF;        // node sub, edges 0..15 (mask bounds garbage)
    int q2x = epack4[rb + 16 + sl] & 0x1FFFF;   // node sub, edges 16..31 (may over-read: ok)
    float dq1 = dis[q1x];                       // dependent gathers, L2-resident
    float dq2 = dis[q2x];
    int cq1 = combo[q1x] << 7;                  // TC byte offset
    int cq2 = combo[q2x] << 7;

    // scalar row pointers
    int r0 = __builtin_amdgcn_readfirstlane(rowptr[v0]);
    int r1 = __builtin_amdgcn_readfirstlane(rowptr[v0 + 1]);
    int r2 = __builtin_amdgcn_readfirstlane(rowptr[v0 + 2]);
    int r3 = __builtin_amdgcn_readfirstlane(rowptr[v0 + 3]);
    int r4 = __builtin_amdgcn_readfirstlane(rowptr[v0 + 4]);

    // per-node epilogue scalars (issue early)
    float d0 = dis[v0], d1 = dis[v0 + 1], d2 = dis[v0 + 2], d3 = dis[v0 + 3];
    int o0 = combo[v0] << 7, o1 = combo[v0 + 1] << 7;
    int o2 = combo[v0 + 2] << 7, o3 = combo[v0 + 3] << 7;
    float bias = b1[lane];

    // B fragments of W2 for this wave's 16 output cols (built once, from global)
    f16x8 bf0, bf1;
    {
        int colw = (w << 4) + (lane & 15);
        int kb = (lane >> 4) * 8;
#pragma unroll
        for (int i = 0; i < 8; ++i) {
            bf0[i] = (_Float16)W2[(kb + i) * HID + colw];
            bf1[i] = (_Float16)W2[(32 + kb + i) * HID + colw];
        }
    }

    // stage TC table to LDS
    {
        const int4* s4 = (const int4*)TCh;
        int4* dd4 = (int4*)TCs;
        for (int i = t; i < NCOMBO * HID * 2 / 16; i += 256) dd4[i] = s4[i];
    }
    __syncthreads();   // also drains the edge + dis + combo prefetch

    AGG_NODE(0, r0, r1, d0, o0)
    AGG_NODE(1, r1, r2, d1, o1)
    AGG_NODE(2, r2, r3, d2, o2)
    AGG_NODE(3, r3, r4, d3, o3)

    __syncthreads();   // all 16 rows of xsA ready

    // A fragments: row = lane&15 (node), k = (lane>>4)*8 + i  (+32 for 2nd MFMA)
    const __half* xa = &xsA[lane & 15][0];
    f16x8 a0 = *(const f16x8*)(xa + (lane >> 4) * 8);
    f16x8 a1 = *(const f16x8*)(xa + 32 + (lane >> 4) * 8);
    f32x4 dacc = {0.0f, 0.0f, 0.0f, 0.0f};
    dacc = __builtin_amdgcn_mfma_f32_16x16x32_f16(a0, bf0, dacc, 0, 0, 0);
    dacc = __builtin_amdgcn_mfma_f32_16x16x32_f16(a1, bf1, dacc, 0, 0, 0);

    // D: col = lane&15 (within wave's 16-col block), row = (lane>>4)*4 + i (node)
    {
        int colg = (w << 4) + (lane & 15);
#pragma unroll
        for (int i = 0; i < 4; ++i)
            Dst[((lane >> 4) * 4 + i) * 64 + colg] = __float2half_rn(dacc[i]);
    }
    __syncthreads();

    // coalesced block store: 16 nodes x 64 feats fp16 = 2048 B contiguous
    {
        const uint2* ds2 = (const uint2*)Dst;
        uint2* go = (uint2*)(h2s + (size_t)vb * HID);
        go[t] = ds2[t];
    }
}

// ---------------- per-node edge accumulate for layer 2 ----------------
// sx: lane i holds epack4[rs+i] (plain src).  Broadcast h2s byte-offset per edge
// via readlane; gathers are per-lane vector loads (vmcnt, 8-deep in flight).
__device__ __forceinline__ float agg2_node(const int* __restrict__ epack4, int sx,
                                           int rs, int re, int lane, int lane2,
                                           const __half* __restrict__ h2s) {
    float acc = 0.0f;
    int p = rs;
    for (;;) {
        int avail = re - p;
        int cnt = avail > 64 ? 64 : avail;
        int vo = sx << 7;                  // src*128 byte offset
        int j = 0;
        for (; j + 8 <= cnt; j += 8) {
            float g[8];
#pragma unroll
            for (int i = 0; i < 8; ++i) {
                int off = __builtin_amdgcn_readlane(vo, j + i);
                g[i] = __half2float(*(const __half*)((const char*)h2s + (off + lane2)));
            }
#pragma unroll
            for (int i = 0; i < 8; ++i) acc += g[i];
        }
        if (j < cnt) {
#pragma unroll
            for (int i = 0; i < 8; ++i) {
                int jj = j + i;
                int off = __builtin_amdgcn_readlane(vo, jj & 63);
                float gv = __half2float(*(const __half*)((const char*)h2s + (off + lane2)));
                acc += (jj < cnt) ? gv : 0.0f;
            }
        }
        p += 64;
        if (p >= re) break;
        int idx = p + lane;
        idx = idx < N_EDGES ? idx : N_EDGES - 1;
        sx = epack4[idx];
    }
    return acc;
}

// ---------------- layer-2 aggregate + pool: 4 nodes/wave, run-merged atomics ----------------
__global__ __launch_bounds__(256, 8) void agg2_pool_kernel(
    const int* __restrict__ epack4, const int* __restrict__ rowptr,
    const __half* __restrict__ h2s, const float* __restrict__ dis,
    const float* __restrict__ b2, const int* __restrict__ batch,
    float* __restrict__ pooled) {
    int t = threadIdx.x, lane = t & 63, w = t >> 6;
    int lane2 = lane * 2;
    int v0 = (blockIdx.x * 4 + w) * 4;   // grid 6250

    int r0 = __builtin_amdgcn_readfirstlane(rowptr[v0]);
    int r1 = __builtin_amdgcn_readfirstlane(rowptr[v0 + 1]);
    int r2 = __builtin_amdgcn_readfirstlane(rowptr[v0 + 2]);
    int r3 = __builtin_amdgcn_readfirstlane(rowptr[v0 + 3]);
    int r4 = __builtin_amdgcn_readfirstlane(rowptr[v0 + 4]);

    int ia = r0 + lane; ia = ia < N_EDGES ? ia : N_EDGES - 1;
    int ib = r1 + lane; ib = ib < N_EDGES ? ib : N_EDGES - 1;
    int ic = r2 + lane; ic = ic < N_EDGES ? ic : N_EDGES - 1;
    int id = r3 + lane; id = id < N_EDGES ? id : N_EDGES - 1;
    int sa = epack4[ia];
    int sb = epack4[ib];
    int sc = epack4[ic];
    int sd = epack4[id];

    float bv = b2[lane];
    float acc0 = agg2_node(epack4, sa, r0, r1, lane, lane2, h2s);
    float acc1 = agg2_node(epack4, sb, r1, r2, lane, lane2, h2s);
    float acc2 = agg2_node(epack4, sc, r2, r3, lane, lane2, h2s);
    float acc3 = agg2_node(epack4, sd, r3, r4, lane, lane2, h2s);

#define AGG2_VAL(V, ACC, OUT)                                                  \
    {                                                                          \
        float dv = dis[V];                                                     \
        float self = __half2float(h2s[(size_t)(V) * HID + lane]);              \
        float val = dv * ((ACC) + self) + bv;                                  \
        OUT = val > 0.0f ? val : 0.0f;                                         \
    }
    float val0, val1, val2, val3;
    AGG2_VAL(v0, acc0, val0)
    AGG2_VAL(v0 + 1, acc1, val1)
    AGG2_VAL(v0 + 2, acc2, val2)
    AGG2_VAL(v0 + 3, acc3, val3)
#undef AGG2_VAL

    int g0 = __builtin_amdgcn_readfirstlane(batch[v0]);
    int g1 = __builtin_amdgcn_readfirstlane(batch[v0 + 1]);
    int g2 = __builtin_amdgcn_readfirstlane(batch[v0 + 2]);
    int g3 = __builtin_amdgcn_readfirstlane(batch[v0 + 3]);
    // batch is sorted: merge same-graph contributions into one atomic per run
    float s = val0; int g = g0;
    if (g1 == g) { s += val1; } else { unsafeAtomicAdd(&pooled[g * HID + lane], s); g = g1; s = val1; }
    if (g2 == g) { s += val2; } else { unsafeAtomicAdd(&pooled[g * HID + lane], s); g = g2; s = val2; }
    if (g3 == g) { s += val3; } else { unsafeAtomicAdd(&pooled[g * HID + lane], s); g = g3; s = val3; }
    unsafeAtomicAdd(&pooled[g * HID + lane], s);
}

// ---------------- logits ----------------
__global__ __launch_bounds__(64) void logits_kernel(
    const float* __restrict__ pooled, const int* __restrict__ gstart,
    const float* __restrict__ Wl, const float* __restrict__ bl,
    float* __restrict__ out) {
    __shared__ float row[HID];
    int g = blockIdx.x, t = threadIdx.x;
    int c = gstart[g + 1] - gstart[g]; if (c < 1) c = 1;
    row[t] = pooled[g * HID + t] / (float)c;
    __syncthreads();
    if (t < N_CLASSES) {
        float acc = bl[t];
#pragma unroll
        for (int k = 0; k < HID; ++k) acc = fmaf(row[k], Wl[k * N_CLASSES + t], acc);
        out[g * N_CLASSES + t] = acc;
    }
}

extern "C" void kernel_launch(void* const* d_in, const int* in_sizes, int n_in,
                              void* d_out, int out_size, void* d_ws, size_t ws_size,
                              hipStream_t stream) {
    const int*   shape_id = (const int*)d_in[0];
    const int*   color_id = (const int*)d_in[1];
    const int*   edge_idx = (const int*)d_in[2];
    const int*   batch    = (const int*)d_in[3];
    const float* st       = (const float*)d_in[4];
    const float* ct       = (const float*)d_in[5];
    const float* W1       = (const float*)d_in[6];
    const float* b1       = (const float*)d_in[7];
    const float* W2       = (const float*)d_in[8];
    const float* b2       = (const float*)d_in[9];
    const float* Wl       = (const float*)d_in[10];
    const float* bl       = (const float*)d_in[11];
    float* out = (float*)d_out;

    const int* src = edge_idx;
    const int* dst = edge_idx + N_EDGES;

    // workspace layout
    char* ws = (char*)d_ws;
    int*    combo   = (int*)   (ws + 0);            //   400,384 B
    float*  dis     = (float*) (ws + 400384);       //   400,384 B
    int*    gstart  = (int*)   (ws + 801792);       //     4,112 B
    int*    rowptr  = (int*)   (ws + 1201152);      //   400,384 B
    __half* TCh     = (__half*)(ws + 1603584);      //    19,968 B
    float*  pooled  = (float*) (ws + 1623552);      //   262,144 B
    int*    gcur    = (int*)   (ws + 1889792);      //     1,024 B
    int*    epack4  = (int*)   (ws + 1890816);      //  6,400,000 B (4B/edge, plain src)
    int*    gbinx   = (int*)   (ws + 14690816);     //  7,340,032 B
    int*    gbiny   = (int*)   (ws + 22030848);     //  7,340,032 B
    __half* h2s     = (__half*)(ws + 29370880);     // 12,800,000 B (total ~42.2 MB)

    // 1. combo + batch boundaries + TC table + pooled/gcur zeroing (fused)
    prep_kernel<<<SCAN_BLOCKS, 256, 0, stream>>>(shape_id, color_id, batch, combo, gstart,
                                                 st, ct, W1, TCh, pooled, gcur);

    // 2. bin edges by dst-bucket (raw src/dst, vectorized loads)
    binA_kernel<<<(N_EDGES + EPB - 1) / EPB, 512, 0, stream>>>(src, dst, gcur,
                                                               gbinx, gbiny);

    // 3. merged: degrees + dis + rowptr + CSR scatter (int4 streams)
    bucket_scatter_kernel<<<NBUCK, 1024, 0, stream>>>(gbinx, gbiny, gcur,
                                                      dis, rowptr, epack4);

    // 4. fused layer-1 aggregate + MFMA mm2 -> h2s (16 nodes/block)
    agg1_mm2_kernel<<<6250, 256, 0, stream>>>(epack4, rowptr, combo, dis, TCh, W2, b1, h2s);

    // 5. layer-2 aggregate + pool (8 waves/EU, plain-src edge reads)
    agg2_pool_kernel<<<6250, 256, 0, stream>>>(epack4, rowptr, h2s, dis, b2, batch, pooled);

    // 6. logits (counts from gstart boundaries)
    logits_kernel<<<N_GRAPHS, 64, 0, stream>>>(pooled, gstart, Wl, bl, out);
}